// Round 1
// baseline (466.956 us; speedup 1.0000x reference)
//
#include <hip/hip_runtime.h>

typedef unsigned short u16;
typedef __attribute__((ext_vector_type(8))) short bf16x8;
typedef __attribute__((ext_vector_type(4))) float f32x4;

#define MFMA(a, b, c) __builtin_amdgcn_mfma_f32_16x16x32_bf16((a), (b), (c), 0, 0, 0)

// ---- LDS layout (u16 element indices), all bf16 tiles stride 136 (272B = 17*16B: 16B-aligned, conflict-reduced)
#define XHO   0              // x_hi [112][136]; reused as attn-out bf16 [112][136] before proj
#define WSTO  15232          // staged weights, 21760 u16 (43520 B)
#define WQH   (WSTO + 0)     // [32][136] each
#define WQL   (WSTO + 4352)
#define WKH   (WSTO + 8704)
#define WKL   (WSTO + 13056)
#define WVH   (WSTO + 17408)
#define QHO   36992          // qn hi [112][40]
#define QLO   41472
#define KHO   45952
#define KLO   50432
#define VTO   54912          // v transposed [32][136]
#define PO    59264          // P bf16 [112][136]
#define LDS_BYTES 148992

__device__ __forceinline__ u16 f2bu(float f) {  // f32 -> bf16 RNE
  union { float f; unsigned u; } v; v.f = f;
  unsigned r = v.u + 0x7fffu + ((v.u >> 16) & 1u);
  return (u16)(r >> 16);
}
__device__ __forceinline__ float bu2f(u16 u) {
  union { unsigned u; float f; } v; v.u = ((unsigned)u) << 16; return v.f;
}
// shift-mask region code for token tok of window with boundary flags (bd,bh,bw)
__device__ __forceinline__ int maskcode(int tok, int bd, int bh, int bw) {
  int d = tok / 49, rem = tok - d * 49, hh = rem / 7, w = rem - hh * 7;
  int rd = bd ? (d == 0 ? 1 : 2) : 0;
  int rh = bh ? (hh < 4 ? 1 : 2) : 0;
  int rw = bw ? (w < 4 ? 1 : 2) : 0;
  return rd * 9 + rh * 3 + rw;
}

// ---------- prep: CPB MLP -> bias_tab[507][4] ----------
__global__ void cpb_mlp(const float* __restrict__ w1, const float* __restrict__ b1,
                        const float* __restrict__ w2, float* __restrict__ btab) {
  const int m = blockIdx.x;          // 0..506
  const int k = threadIdx.x;         // 0..511
  const int i0 = m / 169, rm = m % 169, i1 = rm / 13, i2 = rm % 13;
  float c0 = (float)(i0 - 1) * 8.0f;
  float c1 = (float)(i1 - 6) * (8.0f / 6.0f);
  float c2 = (float)(i2 - 6) * (8.0f / 6.0f);
  float t0 = (c0 > 0.f ? 1.f : (c0 < 0.f ? -1.f : 0.f)) * log2f(fabsf(c0) + 1.f) * (1.f / 3.f);
  float t1 = (c1 > 0.f ? 1.f : (c1 < 0.f ? -1.f : 0.f)) * log2f(fabsf(c1) + 1.f) * (1.f / 3.f);
  float t2 = (c2 > 0.f ? 1.f : (c2 < 0.f ? -1.f : 0.f)) * log2f(fabsf(c2) + 1.f) * (1.f / 3.f);
  float hid = fmaxf(w1[k * 3 + 0] * t0 + w1[k * 3 + 1] * t1 + w1[k * 3 + 2] * t2 + b1[k], 0.f);
  __shared__ float red[4][8];
#pragma unroll
  for (int h = 0; h < 4; ++h) {
    float v = hid * w2[h * 512 + k];
    for (int mm = 1; mm < 64; mm <<= 1) v += __shfl_xor(v, mm);
    if ((k & 63) == 0) red[h][k >> 6] = v;
  }
  __syncthreads();
  if (k < 4) {
    float s = 0.f;
#pragma unroll
    for (int j = 0; j < 8; ++j) s += red[k][j];
    btab[m * 4 + k] = s;
  }
}

// ---------- prep: rpb[4][98][98] = 16*sigmoid(bias_tab[idx(i,j)][h]) ----------
__global__ void build_rpb(const float* __restrict__ btab, float* __restrict__ rpb) {
  int n = blockIdx.x * 256 + threadIdx.x;
  if (n >= 4 * 98 * 98) return;
  int h = n / 9604, r2 = n % 9604, i = r2 / 98, j = r2 % 98;
  int di = i / 49, ri = i % 49, hi_ = ri / 7, wi = ri % 7;
  int dj = j / 49, rj = j % 49, hj = rj / 7, wj = rj % 7;
  int idx = (di - dj + 1) * 169 + (hi_ - hj + 6) * 13 + (wi - wj + 6);
  float v = btab[idx * 4 + h];
  rpb[n] = 16.f / (1.f + expf(-v));
}

// ---------- prep: pack qkv weights per head: [h][5blk][32][136] bf16 (q_hi,q_lo,k_hi,k_lo,v_hi)
__global__ void pack_wqkv(const float* __restrict__ qkvw, u16* __restrict__ dst) {
  int bid = blockIdx.x;                       // 640 = 4h * 5blk * 32r
  int h = bid / 160, rem = bid % 160, blk = rem / 32, r = rem % 32;
  int srow = (blk < 2 ? 0 : (blk < 4 ? 128 : 256)) + h * 32 + r;
  bool lo = (blk == 1) || (blk == 3);
  int c = threadIdx.x;                        // 0..135
  float v = (c < 128) ? qkvw[srow * 128 + c] : 0.f;
  u16 hi = f2bu(v);
  u16 outv = lo ? f2bu(v - bu2f(hi)) : hi;
  dst[h * 21760 + blk * 4352 + r * 136 + c] = outv;
}

// ---------- prep: pack proj weights [128][136] bf16 (row c = output col) ----------
__global__ void pack_wproj(const float* __restrict__ pw, u16* __restrict__ dst) {
  int c = blockIdx.x;                         // 0..127
  int m = threadIdx.x;                        // 0..135
  float v = (m < 128) ? pw[c * 128 + m] : 0.f;
  dst[c * 136 + m] = f2bu(v);
}

// ---------- main fused kernel: one block per window ----------
__global__ __launch_bounds__(448) void swin_main(
    const float* __restrict__ xg, const float* __restrict__ qkvb,
    const float* __restrict__ projb, const float* __restrict__ lscale,
    const float* __restrict__ rpb, const u16* __restrict__ wqkv,
    const u16* __restrict__ wproj, float* __restrict__ outg) {
  extern __shared__ u16 lds[];
  const int tid = threadIdx.x;
  const int wv = tid >> 6;
  const int l = tid & 63;
  const int l15 = l & 15;
  const int lg = l >> 4;
  const int wid = blockIdx.x;
  const int iw = wid & 15, ih = (wid >> 4) & 15, id = wid >> 8;
  const int bd = (id == 7), bh = (ih == 15), bw = (iw == 15);

  // ---- phase 0: gather shifted-window x -> bf16 LDS; zero pads ----
  for (int it = tid; it < 98 * 32; it += 448) {
    int row = it >> 5, c4 = it & 31;
    int d = row / 49, rem = row - d * 49, hh = rem / 7, w2 = rem - hh * 7;
    int pd = (id * 2 + d + 1) & 15;
    int ph = ih * 7 + hh + 3; if (ph >= 112) ph -= 112;
    int pw = iw * 7 + w2 + 3; if (pw >= 112) pw -= 112;
    const float4 v = *(const float4*)(xg + (((pd * 112 + ph) * 112 + pw) << 7) + c4 * 4);
    ushort4 u;
    u.x = f2bu(v.x); u.y = f2bu(v.y); u.z = f2bu(v.z); u.w = f2bu(v.w);
    *(ushort4*)(&lds[XHO + row * 136 + c4 * 4]) = u;
  }
  for (int it = tid; it < 14 * 136; it += 448) lds[XHO + 98 * 136 + it] = 0;
  for (int it = tid; it < 32 * 24; it += 448) lds[VTO + (it / 24) * 136 + 112 + (it % 24)] = 0;
  for (int it = tid; it < 112 * 24; it += 448) lds[PO + (it / 24) * 136 + 112 + (it % 24)] = 0;

  const f32x4 zf = {0.f, 0.f, 0.f, 0.f};
  f32x4 oacc[4][2];
#pragma unroll
  for (int h = 0; h < 4; ++h) { oacc[h][0] = zf; oacc[h][1] = zf; }

  int rcode[4];
#pragma unroll
  for (int r = 0; r < 4; ++r) rcode[r] = maskcode(16 * wv + lg * 4 + r, bd, bh, bw);
  int ccode[7];
#pragma unroll
  for (int c = 0; c < 7; ++c) ccode[c] = maskcode(16 * c + l15, bd, bh, bw);

#pragma unroll
  for (int h = 0; h < 4; ++h) {
    // ---- stage this head's packed weights into LDS ----
    {
      const uint4* src = (const uint4*)(wqkv + h * 21760);
      uint4* dst = (uint4*)(&lds[WSTO]);
      for (int it = tid; it < 2720; it += 448) dst[it] = src[it];
    }
    __syncthreads();  // weights ready; also fences prev head's PV reads of VT/P

    const float scale = __expf(fminf(lscale[h], 4.60517019f));

    // ---- GEMM1: qkv head slice. q,k weight-rounding compensated (hi+lo) ----
    f32x4 aq0 = zf, aq1 = zf, ak0 = zf, ak1 = zf, av0 = zf, av1 = zf;
    const int arow = 16 * wv + l15;
#pragma unroll
    for (int ks = 0; ks < 4; ++ks) {
      const int k0 = ks * 32 + lg * 8;
      const bf16x8 xa = *(const bf16x8*)(&lds[XHO + arow * 136 + k0]);
      bf16x8 b;
      b = *(const bf16x8*)(&lds[WQH + l15 * 136 + k0]);        aq0 = MFMA(xa, b, aq0);
      b = *(const bf16x8*)(&lds[WQL + l15 * 136 + k0]);        aq0 = MFMA(xa, b, aq0);
      b = *(const bf16x8*)(&lds[WQH + (16 + l15) * 136 + k0]); aq1 = MFMA(xa, b, aq1);
      b = *(const bf16x8*)(&lds[WQL + (16 + l15) * 136 + k0]); aq1 = MFMA(xa, b, aq1);
      b = *(const bf16x8*)(&lds[WKH + l15 * 136 + k0]);        ak0 = MFMA(xa, b, ak0);
      b = *(const bf16x8*)(&lds[WKL + l15 * 136 + k0]);        ak0 = MFMA(xa, b, ak0);
      b = *(const bf16x8*)(&lds[WKH + (16 + l15) * 136 + k0]); ak1 = MFMA(xa, b, ak1);
      b = *(const bf16x8*)(&lds[WKL + (16 + l15) * 136 + k0]); ak1 = MFMA(xa, b, ak1);
      b = *(const bf16x8*)(&lds[WVH + l15 * 136 + k0]);        av0 = MFMA(xa, b, av0);
      b = *(const bf16x8*)(&lds[WVH + (16 + l15) * 136 + k0]); av1 = MFMA(xa, b, av1);
    }
    // epilogue: bias, cosine-normalize (+fold scale into q), split-store qn/kn, store v^T
    const float qb0 = qkvb[h * 32 + l15];
    const float qb1 = qkvb[h * 32 + 16 + l15];
    const float vb0 = qkvb[256 + h * 32 + l15];
    const float vb1 = qkvb[256 + h * 32 + 16 + l15];
#pragma unroll
    for (int r = 0; r < 4; ++r) { aq0[r] += qb0; aq1[r] += qb1; av0[r] += vb0; av1[r] += vb1; }
#pragma unroll
    for (int r = 0; r < 4; ++r) {
      const int row = 16 * wv + lg * 4 + r;
      float s = aq0[r] * aq0[r] + aq1[r] * aq1[r];
      s += __shfl_xor(s, 1); s += __shfl_xor(s, 2); s += __shfl_xor(s, 4); s += __shfl_xor(s, 8);
      float rn = scale / fmaxf(sqrtf(s), 1e-12f);
      float q0 = aq0[r] * rn, q1 = aq1[r] * rn;
      u16 u0 = f2bu(q0), u1 = f2bu(q1);
      lds[QHO + row * 40 + l15] = u0;
      lds[QHO + row * 40 + 16 + l15] = u1;
      lds[QLO + row * 40 + l15] = f2bu(q0 - bu2f(u0));
      lds[QLO + row * 40 + 16 + l15] = f2bu(q1 - bu2f(u1));
      float sk = ak0[r] * ak0[r] + ak1[r] * ak1[r];
      sk += __shfl_xor(sk, 1); sk += __shfl_xor(sk, 2); sk += __shfl_xor(sk, 4); sk += __shfl_xor(sk, 8);
      float rk = 1.f / fmaxf(sqrtf(sk), 1e-12f);
      float k0v = ak0[r] * rk, k1v = ak1[r] * rk;
      u16 ku0 = f2bu(k0v), ku1 = f2bu(k1v);
      lds[KHO + row * 40 + l15] = ku0;
      lds[KHO + row * 40 + 16 + l15] = ku1;
      lds[KLO + row * 40 + l15] = f2bu(k0v - bu2f(ku0));
      lds[KLO + row * 40 + 16 + l15] = f2bu(k1v - bu2f(ku1));
    }
    {
      ushort4 v0, v1;
      v0.x = f2bu(av0[0]); v0.y = f2bu(av0[1]); v0.z = f2bu(av0[2]); v0.w = f2bu(av0[3]);
      v1.x = f2bu(av1[0]); v1.y = f2bu(av1[1]); v1.z = f2bu(av1[2]); v1.w = f2bu(av1[3]);
      *(ushort4*)(&lds[VTO + l15 * 136 + 16 * wv + lg * 4]) = v0;
      *(ushort4*)(&lds[VTO + (16 + l15) * 136 + 16 * wv + lg * 4]) = v1;
    }
    __syncthreads();

    // ---- QK^T (3-term split), bias+mask, in-register softmax -> P bf16 ----
    const bf16x8 qh = *(const bf16x8*)(&lds[QHO + (16 * wv + l15) * 40 + lg * 8]);
    const bf16x8 qlo = *(const bf16x8*)(&lds[QLO + (16 * wv + l15) * 40 + lg * 8]);
    f32x4 att[7];
#pragma unroll
    for (int c = 0; c < 7; ++c) {
      const bf16x8 kh = *(const bf16x8*)(&lds[KHO + (16 * c + l15) * 40 + lg * 8]);
      const bf16x8 kl = *(const bf16x8*)(&lds[KLO + (16 * c + l15) * 40 + lg * 8]);
      f32x4 z = zf;
      z = MFMA(qh, kh, z);
      z = MFMA(qlo, kh, z);
      z = MFMA(qh, kl, z);
      att[c] = z;
    }
#pragma unroll
    for (int c = 0; c < 7; ++c) {
      const int j = 16 * c + l15;
#pragma unroll
      for (int r = 0; r < 4; ++r) {
        const int i = 16 * wv + lg * 4 + r;
        float v = att[c][r];
        if (j < 98) {
          if (i < 98) v += rpb[(h * 98 + i) * 98 + j];
          if (rcode[r] != ccode[c]) v -= 100.f;
        } else v = -1e30f;
        att[c][r] = v;
      }
    }
#pragma unroll
    for (int r = 0; r < 4; ++r) {
      const int i = 16 * wv + lg * 4 + r;
      float m = att[0][r];
#pragma unroll
      for (int c = 1; c < 7; ++c) m = fmaxf(m, att[c][r]);
      m = fmaxf(m, __shfl_xor(m, 1)); m = fmaxf(m, __shfl_xor(m, 2));
      m = fmaxf(m, __shfl_xor(m, 4)); m = fmaxf(m, __shfl_xor(m, 8));
      float p[7];
      float s = 0.f;
#pragma unroll
      for (int c = 0; c < 7; ++c) { p[c] = __expf(att[c][r] - m); s += p[c]; }
      s += __shfl_xor(s, 1); s += __shfl_xor(s, 2); s += __shfl_xor(s, 4); s += __shfl_xor(s, 8);
      const float rs = 1.f / s;
#pragma unroll
      for (int c = 0; c < 7; ++c) lds[PO + i * 136 + 16 * c + l15] = f2bu(p[c] * rs);
    }
    __syncthreads();

    // ---- PV: out_h = P @ v  (accumulate in registers across heads) ----
#pragma unroll
    for (int ks = 0; ks < 4; ++ks) {
      const bf16x8 pa = *(const bf16x8*)(&lds[PO + (16 * wv + l15) * 136 + ks * 32 + lg * 8]);
      const bf16x8 vb0f = *(const bf16x8*)(&lds[VTO + l15 * 136 + ks * 32 + lg * 8]);
      const bf16x8 vb1f = *(const bf16x8*)(&lds[VTO + (16 + l15) * 136 + ks * 32 + lg * 8]);
      oacc[h][0] = MFMA(pa, vb0f, oacc[h][0]);
      oacc[h][1] = MFMA(pa, vb1f, oacc[h][1]);
    }
  }  // head loop

  // ---- write attention output bf16 into XH region (x no longer needed) ----
#pragma unroll
  for (int h = 0; h < 4; ++h)
#pragma unroll
    for (int n = 0; n < 2; ++n)
#pragma unroll
      for (int r = 0; r < 4; ++r) {
        const int row = 16 * wv + lg * 4 + r;
        lds[XHO + row * 136 + h * 32 + n * 16 + l15] = f2bu(oacc[h][n][r]);
      }
  // ---- stage proj weights ----
  {
    const uint4* src = (const uint4*)wproj;
    uint4* dst = (uint4*)(&lds[WSTO]);
    for (int it = tid; it < 2176; it += 448) dst[it] = src[it];
  }
  __syncthreads();

  // ---- proj: y = out @ Wp^T + b, scatter with reverse shift/window ----
  f32x4 pr[8];
#pragma unroll
  for (int n = 0; n < 8; ++n) pr[n] = zf;
#pragma unroll
  for (int ks = 0; ks < 4; ++ks) {
    const bf16x8 oa = *(const bf16x8*)(&lds[XHO + (16 * wv + l15) * 136 + ks * 32 + lg * 8]);
#pragma unroll
    for (int n = 0; n < 8; ++n) {
      const bf16x8 wb = *(const bf16x8*)(&lds[WSTO + (16 * n + l15) * 136 + ks * 32 + lg * 8]);
      pr[n] = MFMA(oa, wb, pr[n]);
    }
  }
  int obase[4];
#pragma unroll
  for (int r = 0; r < 4; ++r) {
    const int row = 16 * wv + lg * 4 + r;
    if (row < 98) {
      int d = row / 49, rem = row - d * 49, hh = rem / 7, w2 = rem - hh * 7;
      int pd = (id * 2 + d + 1) & 15;
      int ph = ih * 7 + hh + 3; if (ph >= 112) ph -= 112;
      int pw = iw * 7 + w2 + 3; if (pw >= 112) pw -= 112;
      obase[r] = ((pd * 112 + ph) * 112 + pw) << 7;
    } else obase[r] = -1;
  }
#pragma unroll
  for (int n = 0; n < 8; ++n) {
    const int col = 16 * n + l15;
    const float pb = projb[col];
#pragma unroll
    for (int r = 0; r < 4; ++r) {
      if (obase[r] >= 0) outg[obase[r] + col] = pr[n][r] + pb;
    }
  }
}

extern "C" void kernel_launch(void* const* d_in, const int* in_sizes, int n_in,
                              void* d_out, int out_size, void* d_ws, size_t ws_size,
                              hipStream_t stream) {
  const float* xg = (const float*)d_in[0];
  const float* qkvw = (const float*)d_in[1];
  const float* qkvb = (const float*)d_in[2];
  const float* projw = (const float*)d_in[3];
  const float* projb = (const float*)d_in[4];
  const float* lsc = (const float*)d_in[5];
  const float* w1 = (const float*)d_in[6];
  const float* b1 = (const float*)d_in[7];
  const float* w2 = (const float*)d_in[8];

  char* ws = (char*)d_ws;
  float* rpb = (float*)(ws + 0);          // 153664 B
  float* btab = (float*)(ws + 153664);    // 8112 B
  u16* wq = (u16*)(ws + 161792);          // 174080 B
  u16* wp = (u16*)(ws + 335872);          // 34816 B

  hipFuncSetAttribute((const void*)swin_main, hipFuncAttributeMaxDynamicSharedMemorySize,
                      LDS_BYTES);

  cpb_mlp<<<507, 512, 0, stream>>>(w1, b1, w2, btab);
  build_rpb<<<(4 * 98 * 98 + 255) / 256, 256, 0, stream>>>(btab, rpb);
  pack_wqkv<<<640, 136, 0, stream>>>(qkvw, wq);
  pack_wproj<<<128, 136, 0, stream>>>(projw, wp);
  swin_main<<<2048, 448, LDS_BYTES, stream>>>(xg, qkvb, projb, lsc, rpb, wq, wp,
                                              (float*)d_out);
}

// Round 2
// 319.942 us; speedup vs baseline: 1.4595x; 1.4595x over previous
//
#include <hip/hip_runtime.h>

typedef unsigned short u16;
typedef __attribute__((ext_vector_type(8))) short bf16x8;
typedef __attribute__((ext_vector_type(4))) float f32x4;

#define MFMA(a, b, c) __builtin_amdgcn_mfma_f32_16x16x32_bf16((a), (b), (c), 0, 0, 0)

__device__ __forceinline__ u16 f2bu(float f) {  // f32 -> bf16 RNE
  union { float f; unsigned u; } v; v.f = f;
  unsigned r = v.u + 0x7fffu + ((v.u >> 16) & 1u);
  return (u16)(r >> 16);
}
__device__ __forceinline__ float bu2f(u16 u) {
  union { unsigned u; float f; } v; v.u = ((unsigned)u) << 16; return v.f;
}
__device__ __forceinline__ int maskcode(int tok, int bd, int bh, int bw) {
  int d = tok / 49, rem = tok - d * 49, hh = rem / 7, w = rem - hh * 7;
  int rd = bd ? (d == 0 ? 1 : 2) : 0;
  int rh = bh ? (hh < 4 ? 1 : 2) : 0;
  int rw = bw ? (w < 4 ? 1 : 2) : 0;
  return rd * 9 + rh * 3 + rw;
}

// ---------- prep: CPB MLP -> bias_tab[507][4] ----------
__global__ void cpb_mlp(const float* __restrict__ w1, const float* __restrict__ b1,
                        const float* __restrict__ w2, float* __restrict__ btab) {
  const int m = blockIdx.x;          // 0..506
  const int k = threadIdx.x;         // 0..511
  const int i0 = m / 169, rm = m % 169, i1 = rm / 13, i2 = rm % 13;
  float c0 = (float)(i0 - 1) * 8.0f;
  float c1 = (float)(i1 - 6) * (8.0f / 6.0f);
  float c2 = (float)(i2 - 6) * (8.0f / 6.0f);
  float t0 = (c0 > 0.f ? 1.f : (c0 < 0.f ? -1.f : 0.f)) * log2f(fabsf(c0) + 1.f) * (1.f / 3.f);
  float t1 = (c1 > 0.f ? 1.f : (c1 < 0.f ? -1.f : 0.f)) * log2f(fabsf(c1) + 1.f) * (1.f / 3.f);
  float t2 = (c2 > 0.f ? 1.f : (c2 < 0.f ? -1.f : 0.f)) * log2f(fabsf(c2) + 1.f) * (1.f / 3.f);
  float hid = fmaxf(w1[k * 3 + 0] * t0 + w1[k * 3 + 1] * t1 + w1[k * 3 + 2] * t2 + b1[k], 0.f);
  __shared__ float red[4][8];
#pragma unroll
  for (int h = 0; h < 4; ++h) {
    float v = hid * w2[h * 512 + k];
    for (int mm = 1; mm < 64; mm <<= 1) v += __shfl_xor(v, mm);
    if ((k & 63) == 0) red[h][k >> 6] = v;
  }
  __syncthreads();
  if (k < 4) {
    float s = 0.f;
#pragma unroll
    for (int j = 0; j < 8; ++j) s += red[k][j];
    btab[m * 4 + k] = s;
  }
}

// ---------- prep: rpb[4][98][98] = 16*sigmoid(bias_tab[idx(i,j)][h]) ----------
__global__ void build_rpb(const float* __restrict__ btab, float* __restrict__ rpb) {
  int n = blockIdx.x * 256 + threadIdx.x;
  if (n >= 4 * 98 * 98) return;
  int h = n / 9604, r2 = n % 9604, i = r2 / 98, j = r2 % 98;
  int di = i / 49, ri = i % 49, hi_ = ri / 7, wi = ri % 7;
  int dj = j / 49, rj = j % 49, hj = rj / 7, wj = rj % 7;
  int idx = (di - dj + 1) * 169 + (hi_ - hj + 6) * 13 + (wi - wj + 6);
  float v = btab[idx * 4 + h];
  rpb[n] = 16.f / (1.f + expf(-v));
}

// ---------- prep: pack qkv weights per head: [h][5blk][32][136] bf16 (q_hi,q_lo,k_hi,k_lo,v_hi)
__global__ void pack_wqkv(const float* __restrict__ qkvw, u16* __restrict__ dst) {
  int bid = blockIdx.x;                       // 640 = 4h * 5blk * 32r
  int h = bid / 160, rem = bid % 160, blk = rem / 32, r = rem % 32;
  int srow = (blk < 2 ? 0 : (blk < 4 ? 128 : 256)) + h * 32 + r;
  bool lo = (blk == 1) || (blk == 3);
  int c = threadIdx.x;                        // 0..135
  float v = (c < 128) ? qkvw[srow * 128 + c] : 0.f;
  u16 hi = f2bu(v);
  u16 outv = lo ? f2bu(v - bu2f(hi)) : hi;
  dst[h * 21760 + blk * 4352 + r * 136 + c] = outv;
}

// ---------- prep: pack proj weights [128][136] bf16 (row c = output col) ----------
__global__ void pack_wproj(const float* __restrict__ pw, u16* __restrict__ dst) {
  int c = blockIdx.x;                         // 0..127
  int m = threadIdx.x;                        // 0..135
  float v = (m < 128) ? pw[c * 128 + m] : 0.f;
  dst[c * 136 + m] = f2bu(v);
}

// ---------- attention kernel: one block per (window, head) ----------
// LDS regions (u16 indices):
//  RA [0,15232):      x_bf16 [112][136]  ->  P [112][136]
//  RB [15232,33152):  staged W q/k hi/lo [4][32][136] -> Q/K hi/lo [112][40] x4
//  RC [33152,37504):  staged W v [32][136] -> V^T [32][136]
#define RA 0
#define RB 15232
#define RC 33152
#define ATTN_LDS_BYTES 75008

__global__ __launch_bounds__(448, 4) void swin_attn(
    const float* __restrict__ xg, const float* __restrict__ qkvb,
    const float* __restrict__ lscale, const float* __restrict__ rpb,
    const u16* __restrict__ wqkv, float* __restrict__ aout) {
  extern __shared__ u16 lds[];
  const int tid = threadIdx.x;
  const int wv = tid >> 6;
  const int l = tid & 63;
  const int l15 = l & 15;
  const int lg = l >> 4;
  const int bid = blockIdx.x;
  const int h = bid >> 11;          // head: blocks h*2048..h*2048+2047 -> same XCD per window
  const int win = bid & 2047;
  const int iw = win & 15, ih = (win >> 4) & 15, id = win >> 8;
  const int bd = (id == 7), bh = (ih == 15), bw = (iw == 15);

  // ---- phase 0: gather shifted-window x -> bf16 LDS(RA); stage weights -> RB/RC ----
  for (int it = tid; it < 98 * 32; it += 448) {
    int row = it >> 5, c4 = it & 31;
    int d = row / 49, rem = row - d * 49, hh = rem / 7, w2 = rem - hh * 7;
    int pd = (id * 2 + d + 1) & 15;
    int ph = ih * 7 + hh + 3; if (ph >= 112) ph -= 112;
    int pw = iw * 7 + w2 + 3; if (pw >= 112) pw -= 112;
    const float4 v = *(const float4*)(xg + (((pd * 112 + ph) * 112 + pw) << 7) + c4 * 4);
    ushort4 u;
    u.x = f2bu(v.x); u.y = f2bu(v.y); u.z = f2bu(v.z); u.w = f2bu(v.w);
    *(ushort4*)(&lds[RA + row * 136 + c4 * 4]) = u;
  }
  for (int it = tid; it < 14 * 136; it += 448) lds[RA + 98 * 136 + it] = 0;
  {
    const uint4* src = (const uint4*)(wqkv + h * 21760);
    for (int it = tid; it < 2720; it += 448) {
      uint4 d = src[it];
      int dst = (it < 2176) ? (RB + it * 8) : (RC + (it - 2176) * 8);
      *(uint4*)(&lds[dst]) = d;
    }
  }
  __syncthreads();

  // ---- phase 1: A-frags to regs; GEMM1 (q,k hi/lo-compensated; v plain) ----
  bf16x8 xa[4];
#pragma unroll
  for (int ks = 0; ks < 4; ++ks)
    xa[ks] = *(const bf16x8*)(&lds[RA + (16 * wv + l15) * 136 + ks * 32 + lg * 8]);

  const f32x4 zf = {0.f, 0.f, 0.f, 0.f};
  f32x4 aq0 = zf, aq1 = zf, ak0 = zf, ak1 = zf, av0 = zf, av1 = zf;
#pragma unroll
  for (int ks = 0; ks < 4; ++ks) {
    const int k0 = ks * 32 + lg * 8;
    bf16x8 b;
    b = *(const bf16x8*)(&lds[RB + l15 * 136 + k0]);                 aq0 = MFMA(xa[ks], b, aq0);
    b = *(const bf16x8*)(&lds[RB + 4352 + l15 * 136 + k0]);          aq0 = MFMA(xa[ks], b, aq0);
    b = *(const bf16x8*)(&lds[RB + (16 + l15) * 136 + k0]);          aq1 = MFMA(xa[ks], b, aq1);
    b = *(const bf16x8*)(&lds[RB + 4352 + (16 + l15) * 136 + k0]);   aq1 = MFMA(xa[ks], b, aq1);
    b = *(const bf16x8*)(&lds[RB + 8704 + l15 * 136 + k0]);          ak0 = MFMA(xa[ks], b, ak0);
    b = *(const bf16x8*)(&lds[RB + 13056 + l15 * 136 + k0]);         ak0 = MFMA(xa[ks], b, ak0);
    b = *(const bf16x8*)(&lds[RB + 8704 + (16 + l15) * 136 + k0]);   ak1 = MFMA(xa[ks], b, ak1);
    b = *(const bf16x8*)(&lds[RB + 13056 + (16 + l15) * 136 + k0]);  ak1 = MFMA(xa[ks], b, ak1);
    b = *(const bf16x8*)(&lds[RC + l15 * 136 + k0]);                 av0 = MFMA(xa[ks], b, av0);
    b = *(const bf16x8*)(&lds[RC + (16 + l15) * 136 + k0]);          av1 = MFMA(xa[ks], b, av1);
  }
  __syncthreads();  // all weight reads done -> RB/RC writable

  // ---- phase 2: bias, cosine-normalize (scale folded into q), split-store, V^T ----
  const float scale = __expf(fminf(lscale[h], 4.60517019f));
  const float qb0 = qkvb[h * 32 + l15];
  const float qb1 = qkvb[h * 32 + 16 + l15];
  const float vb0 = qkvb[256 + h * 32 + l15];
  const float vb1 = qkvb[256 + h * 32 + 16 + l15];
#pragma unroll
  for (int r = 0; r < 4; ++r) { aq0[r] += qb0; aq1[r] += qb1; av0[r] += vb0; av1[r] += vb1; }
  const int QHO = RB, QLO = RB + 4480, KHO = RB + 8960, KLO = RB + 13440;
#pragma unroll
  for (int r = 0; r < 4; ++r) {
    const int row = 16 * wv + lg * 4 + r;
    float s = aq0[r] * aq0[r] + aq1[r] * aq1[r];
    s += __shfl_xor(s, 1); s += __shfl_xor(s, 2); s += __shfl_xor(s, 4); s += __shfl_xor(s, 8);
    float rn = scale / fmaxf(sqrtf(s), 1e-12f);
    float q0 = aq0[r] * rn, q1 = aq1[r] * rn;
    u16 u0 = f2bu(q0), u1 = f2bu(q1);
    lds[QHO + row * 40 + l15] = u0;
    lds[QHO + row * 40 + 16 + l15] = u1;
    lds[QLO + row * 40 + l15] = f2bu(q0 - bu2f(u0));
    lds[QLO + row * 40 + 16 + l15] = f2bu(q1 - bu2f(u1));
    float sk = ak0[r] * ak0[r] + ak1[r] * ak1[r];
    sk += __shfl_xor(sk, 1); sk += __shfl_xor(sk, 2); sk += __shfl_xor(sk, 4); sk += __shfl_xor(sk, 8);
    float rk = 1.f / fmaxf(sqrtf(sk), 1e-12f);
    float k0v = ak0[r] * rk, k1v = ak1[r] * rk;
    u16 ku0 = f2bu(k0v), ku1 = f2bu(k1v);
    lds[KHO + row * 40 + l15] = ku0;
    lds[KHO + row * 40 + 16 + l15] = ku1;
    lds[KLO + row * 40 + l15] = f2bu(k0v - bu2f(ku0));
    lds[KLO + row * 40 + 16 + l15] = f2bu(k1v - bu2f(ku1));
  }
  {
    ushort4 v0, v1;
    v0.x = f2bu(av0[0]); v0.y = f2bu(av0[1]); v0.z = f2bu(av0[2]); v0.w = f2bu(av0[3]);
    v1.x = f2bu(av1[0]); v1.y = f2bu(av1[1]); v1.z = f2bu(av1[2]); v1.w = f2bu(av1[3]);
    *(ushort4*)(&lds[RC + l15 * 136 + 16 * wv + lg * 4]) = v0;
    *(ushort4*)(&lds[RC + (16 + l15) * 136 + 16 * wv + lg * 4]) = v1;
  }
  for (int it = tid; it < 32 * 24; it += 448) lds[RC + (it / 24) * 136 + 112 + (it % 24)] = 0;
  __syncthreads();

  // ---- phase 3: QK^T (3-term split) + rpb + mask + softmax -> P(RA) ----
  int rcode[4];
#pragma unroll
  for (int r = 0; r < 4; ++r) rcode[r] = maskcode(16 * wv + lg * 4 + r, bd, bh, bw);
  int ccode[7];
#pragma unroll
  for (int c = 0; c < 7; ++c) ccode[c] = maskcode(16 * c + l15, bd, bh, bw);

  const bf16x8 qh = *(const bf16x8*)(&lds[QHO + (16 * wv + l15) * 40 + lg * 8]);
  const bf16x8 qlo = *(const bf16x8*)(&lds[QLO + (16 * wv + l15) * 40 + lg * 8]);
  // prefetch rpb (latency hidden under QK^T MFMAs)
  const float* rb_base = rpb + (h * 98) * 98;
  float rv[7][4];
#pragma unroll
  for (int c = 0; c < 7; ++c) {
    const int j = 16 * c + l15;
#pragma unroll
    for (int r = 0; r < 4; ++r) {
      const int i = 16 * wv + lg * 4 + r;
      rv[c][r] = (i < 98 && j < 98) ? rb_base[i * 98 + j] : 0.f;
    }
  }
  f32x4 att[7];
#pragma unroll
  for (int c = 0; c < 7; ++c) {
    const bf16x8 kh = *(const bf16x8*)(&lds[KHO + (16 * c + l15) * 40 + lg * 8]);
    const bf16x8 kl = *(const bf16x8*)(&lds[KLO + (16 * c + l15) * 40 + lg * 8]);
    f32x4 z = zf;
    z = MFMA(qh, kh, z);
    z = MFMA(qlo, kh, z);
    z = MFMA(qh, kl, z);
    att[c] = z;
  }
#pragma unroll
  for (int c = 0; c < 7; ++c) {
    const int j = 16 * c + l15;
#pragma unroll
    for (int r = 0; r < 4; ++r) {
      float v = att[c][r] + rv[c][r];
      if (j < 98) {
        if (rcode[r] != ccode[c]) v -= 100.f;
      } else v = -1e30f;
      att[c][r] = v;
    }
  }
#pragma unroll
  for (int r = 0; r < 4; ++r) {
    const int i = 16 * wv + lg * 4 + r;
    float m = att[0][r];
#pragma unroll
    for (int c = 1; c < 7; ++c) m = fmaxf(m, att[c][r]);
    m = fmaxf(m, __shfl_xor(m, 1)); m = fmaxf(m, __shfl_xor(m, 2));
    m = fmaxf(m, __shfl_xor(m, 4)); m = fmaxf(m, __shfl_xor(m, 8));
    float p[7];
    float s = 0.f;
#pragma unroll
    for (int c = 0; c < 7; ++c) { p[c] = __expf(att[c][r] - m); s += p[c]; }
    s += __shfl_xor(s, 1); s += __shfl_xor(s, 2); s += __shfl_xor(s, 4); s += __shfl_xor(s, 8);
    const float rs = 1.f / s;
#pragma unroll
    for (int c = 0; c < 7; ++c) lds[RA + i * 136 + 16 * c + l15] = f2bu(p[c] * rs);
    lds[RA + i * 136 + 112 + l15] = 0;  // zero P pad cols 112..127
  }
  __syncthreads();

  // ---- phase 4: PV -> scattered f32 store into aout (= d_out) ----
  f32x4 o0 = zf, o1 = zf;
#pragma unroll
  for (int ks = 0; ks < 4; ++ks) {
    const bf16x8 pa = *(const bf16x8*)(&lds[RA + (16 * wv + l15) * 136 + ks * 32 + lg * 8]);
    const bf16x8 v0f = *(const bf16x8*)(&lds[RC + l15 * 136 + ks * 32 + lg * 8]);
    const bf16x8 v1f = *(const bf16x8*)(&lds[RC + (16 + l15) * 136 + ks * 32 + lg * 8]);
    o0 = MFMA(pa, v0f, o0);
    o1 = MFMA(pa, v1f, o1);
  }
#pragma unroll
  for (int r = 0; r < 4; ++r) {
    const int row = 16 * wv + lg * 4 + r;
    if (row < 98) {
      int d = row / 49, rem = row - d * 49, hh = rem / 7, w2 = rem - hh * 7;
      int pd = (id * 2 + d + 1) & 15;
      int ph = ih * 7 + hh + 3; if (ph >= 112) ph -= 112;
      int pw = iw * 7 + w2 + 3; if (pw >= 112) pw -= 112;
      const int ob = (((pd * 112 + ph) * 112 + pw) << 7) + h * 32;
      aout[ob + l15] = o0[r];
      aout[ob + 16 + l15] = o1[r];
    }
  }
}

// ---------- proj kernel: one block per window, in-place on d_out ----------
__global__ __launch_bounds__(448) void swin_proj(const u16* __restrict__ wp,
                                                 const float* __restrict__ projb,
                                                 float* io) {
  __shared__ u16 w[17408];
  const int tid = threadIdx.x;
  const int wv = tid >> 6;
  const int l = tid & 63;
  const int l15 = l & 15;
  const int lg = l >> 4;
  const int win = blockIdx.x;
  const int iw = win & 15, ih = (win >> 4) & 15, id = win >> 8;
  {
    const uint4* src = (const uint4*)wp;
    uint4* dst = (uint4*)w;
    for (int it = tid; it < 2176; it += 448) dst[it] = src[it];
  }
  // per-lane A-row global base (clamp pad rows to a valid address)
  const int arow0 = 16 * wv + l15;
  const int ar = (arow0 < 98) ? arow0 : 97;
  int d = ar / 49, rem = ar - d * 49, hh = rem / 7, w2 = rem - hh * 7;
  int pd = (id * 2 + d + 1) & 15;
  int ph = ih * 7 + hh + 3; if (ph >= 112) ph -= 112;
  int pw = iw * 7 + w2 + 3; if (pw >= 112) pw -= 112;
  const float* abase = io + (((pd * 112 + ph) * 112 + pw) << 7);
  __syncthreads();

  const f32x4 zf = {0.f, 0.f, 0.f, 0.f};
  f32x4 pr[8];
#pragma unroll
  for (int n = 0; n < 8; ++n) pr[n] = zf;
#pragma unroll
  for (int ks = 0; ks < 4; ++ks) {
    const float4 f0 = *(const float4*)(abase + ks * 32 + lg * 8);
    const float4 f1 = *(const float4*)(abase + ks * 32 + lg * 8 + 4);
    bf16x8 oa;
    u16* op = (u16*)&oa;
    op[0] = f2bu(f0.x); op[1] = f2bu(f0.y); op[2] = f2bu(f0.z); op[3] = f2bu(f0.w);
    op[4] = f2bu(f1.x); op[5] = f2bu(f1.y); op[6] = f2bu(f1.z); op[7] = f2bu(f1.w);
#pragma unroll
    for (int n = 0; n < 8; ++n) {
      const bf16x8 wb = *(const bf16x8*)(&w[(16 * n + l15) * 136 + ks * 32 + lg * 8]);
      pr[n] = MFMA(oa, wb, pr[n]);
    }
  }
  int obase[4];
#pragma unroll
  for (int r = 0; r < 4; ++r) {
    const int row = 16 * wv + lg * 4 + r;
    if (row < 98) {
      int d2 = row / 49, rem2 = row - d2 * 49, hh2 = rem2 / 7, w22 = rem2 - hh2 * 7;
      int pd2 = (id * 2 + d2 + 1) & 15;
      int ph2 = ih * 7 + hh2 + 3; if (ph2 >= 112) ph2 -= 112;
      int pw2 = iw * 7 + w22 + 3; if (pw2 >= 112) pw2 -= 112;
      obase[r] = ((pd2 * 112 + ph2) * 112 + pw2) << 7;
    } else obase[r] = -1;
  }
#pragma unroll
  for (int n = 0; n < 8; ++n) {
    const int col = 16 * n + l15;
    const float pb = projb[col];
#pragma unroll
    for (int r = 0; r < 4; ++r) {
      if (obase[r] >= 0) io[obase[r] + col] = pr[n][r] + pb;
    }
  }
}

extern "C" void kernel_launch(void* const* d_in, const int* in_sizes, int n_in,
                              void* d_out, int out_size, void* d_ws, size_t ws_size,
                              hipStream_t stream) {
  const float* xg = (const float*)d_in[0];
  const float* qkvw = (const float*)d_in[1];
  const float* qkvb = (const float*)d_in[2];
  const float* projw = (const float*)d_in[3];
  const float* projb = (const float*)d_in[4];
  const float* lsc = (const float*)d_in[5];
  const float* w1 = (const float*)d_in[6];
  const float* b1 = (const float*)d_in[7];
  const float* w2 = (const float*)d_in[8];

  char* ws = (char*)d_ws;
  float* rpb = (float*)(ws + 0);          // 153,664 B
  float* btab = (float*)(ws + 153664);    // 8,112 B
  u16* wq = (u16*)(ws + 161792);          // 174,080 B
  u16* wp = (u16*)(ws + 335872);          // 34,816 B
  float* io = (float*)d_out;

  hipFuncSetAttribute((const void*)swin_attn, hipFuncAttributeMaxDynamicSharedMemorySize,
                      ATTN_LDS_BYTES);

  cpb_mlp<<<507, 512, 0, stream>>>(w1, b1, w2, btab);
  build_rpb<<<(4 * 98 * 98 + 255) / 256, 256, 0, stream>>>(btab, rpb);
  pack_wqkv<<<640, 136, 0, stream>>>(qkvw, wq);
  pack_wproj<<<128, 136, 0, stream>>>(projw, wp);
  swin_attn<<<8192, 448, ATTN_LDS_BYTES, stream>>>(xg, qkvb, lsc, rpb, wq, io);
  swin_proj<<<2048, 448, 0, stream>>>(wp, projb, io);
}

// Round 4
// 290.658 us; speedup vs baseline: 1.6065x; 1.1008x over previous
//
#include <hip/hip_runtime.h>

typedef unsigned short u16;
typedef __attribute__((ext_vector_type(8))) short bf16x8;
typedef __attribute__((ext_vector_type(4))) float f32x4;

#define MFMA(a, b, c) __builtin_amdgcn_mfma_f32_16x16x32_bf16((a), (b), (c), 0, 0, 0)
#define LOG2E 1.4426950408889634f

__device__ __forceinline__ u16 f2bu(float f) {  // f32 -> bf16 RNE
  union { float f; unsigned u; } v; v.f = f;
  unsigned r = v.u + 0x7fffu + ((v.u >> 16) & 1u);
  return (u16)(r >> 16);
}
__device__ __forceinline__ float bu2f(u16 u) {
  union { unsigned u; float f; } v; v.u = ((unsigned)u) << 16; return v.f;
}
__device__ __forceinline__ int maskcode(int tok, int bd, int bh, int bw) {
  int d = tok / 49, rem = tok - d * 49, hh = rem / 7, w = rem - hh * 7;
  int rd = bd ? (d == 0 ? 1 : 2) : 0;
  int rh = bh ? (hh < 4 ? 1 : 2) : 0;
  int rw = bw ? (w < 4 ? 1 : 2) : 0;
  return rd * 9 + rh * 3 + rw;
}

// ---------- prep: CPB MLP -> bias_tab[507][4] ----------
__global__ void cpb_mlp(const float* __restrict__ w1, const float* __restrict__ b1,
                        const float* __restrict__ w2, float* __restrict__ btab) {
  const int m = blockIdx.x;          // 0..506
  const int k = threadIdx.x;         // 0..511
  const int i0 = m / 169, rm = m % 169, i1 = rm / 13, i2 = rm % 13;
  float c0 = (float)(i0 - 1) * 8.0f;
  float c1 = (float)(i1 - 6) * (8.0f / 6.0f);
  float c2 = (float)(i2 - 6) * (8.0f / 6.0f);
  float t0 = (c0 > 0.f ? 1.f : (c0 < 0.f ? -1.f : 0.f)) * log2f(fabsf(c0) + 1.f) * (1.f / 3.f);
  float t1 = (c1 > 0.f ? 1.f : (c1 < 0.f ? -1.f : 0.f)) * log2f(fabsf(c1) + 1.f) * (1.f / 3.f);
  float t2 = (c2 > 0.f ? 1.f : (c2 < 0.f ? -1.f : 0.f)) * log2f(fabsf(c2) + 1.f) * (1.f / 3.f);
  float hid = fmaxf(w1[k * 3 + 0] * t0 + w1[k * 3 + 1] * t1 + w1[k * 3 + 2] * t2 + b1[k], 0.f);
  __shared__ float red[4][8];
#pragma unroll
  for (int h = 0; h < 4; ++h) {
    float v = hid * w2[h * 512 + k];
    for (int mm = 1; mm < 64; mm <<= 1) v += __shfl_xor(v, mm);
    if ((k & 63) == 0) red[h][k >> 6] = v;
  }
  __syncthreads();
  if (k < 4) {
    float s = 0.f;
#pragma unroll
    for (int j = 0; j < 8; ++j) s += red[k][j];
    btab[m * 4 + k] = s;
  }
}

// ---------- prep: rpb[4][98][98] = log2e * 16*sigmoid(bias_tab[idx(i,j)][h]) ----------
__global__ void build_rpb(const float* __restrict__ btab, float* __restrict__ rpb) {
  int n = blockIdx.x * 256 + threadIdx.x;
  if (n >= 4 * 98 * 98) return;
  int h = n / 9604, r2 = n % 9604, i = r2 / 98, j = r2 % 98;
  int di = i / 49, ri = i % 49, hi_ = ri / 7, wi = ri % 7;
  int dj = j / 49, rj = j % 49, hj = rj / 7, wj = rj % 7;
  int idx = (di - dj + 1) * 169 + (hi_ - hj + 6) * 13 + (wi - wj + 6);
  float v = btab[idx * 4 + h];
  rpb[n] = (16.f / (1.f + expf(-v))) * LOG2E;
}

// ---------- prep: pack qkv weights per head: [h][5blk][32][136] bf16 (q_hi,q_lo,k_hi,k_lo,v_hi)
__global__ void pack_wqkv(const float* __restrict__ qkvw, u16* __restrict__ dst) {
  int bid = blockIdx.x;                       // 640 = 4h * 5blk * 32r
  int h = bid / 160, rem = bid % 160, blk = rem / 32, r = rem % 32;
  int srow = (blk < 2 ? 0 : (blk < 4 ? 128 : 256)) + h * 32 + r;
  bool lo = (blk == 1) || (blk == 3);
  int c = threadIdx.x;                        // 0..135
  float v = (c < 128) ? qkvw[srow * 128 + c] : 0.f;
  u16 hi = f2bu(v);
  u16 outv = lo ? f2bu(v - bu2f(hi)) : hi;
  dst[h * 21760 + blk * 4352 + r * 136 + c] = outv;
}

// ---------- prep: pack proj weights [128][136] bf16 (row c = output col) ----------
__global__ void pack_wproj(const float* __restrict__ pw, u16* __restrict__ dst) {
  int c = blockIdx.x;                         // 0..127
  int m = threadIdx.x;                        // 0..135
  float v = (m < 128) ? pw[c * 128 + m] : 0.f;
  dst[c * 136 + m] = f2bu(v);
}

// ---------- attention kernel: one block per (window, head), win-major ----------
// LDS pool 22016 u16 (44032 B -> 3 blocks/CU):
//   phase1: staged W [5][32][136] = 21760 @0
//   phase2+: Qhi@0, Qlo@4480, Khi@8960, Klo@13440 (each [112][40]); VT@17920 [32][128] swz
//   phase4: P [112][128] swz @0 (overlays Q/K after barrier B4)
#define QHI 0
#define QLO 4480
#define KHI 8960
#define KLO 13440
#define VT  17920
#define PIDX(i, t) ((i) * 128 + ((t) ^ (((i) & 7) << 3)))
#define VIDX(d, t) (VT + (d) * 128 + ((t) ^ (((d) & 7) << 3)))

__global__ __launch_bounds__(448, 6) void swin_attn(
    const float* __restrict__ xg, const float* __restrict__ qkvb,
    const float* __restrict__ lscale, const float* __restrict__ rpb,
    const u16* __restrict__ wqkv, float* __restrict__ aout) {
  __shared__ u16 lds[22016];
  const int tid = threadIdx.x;
  const int wv = tid >> 6;
  const int l = tid & 63;
  const int l15 = l & 15;
  const int lg = l >> 4;
  const int bid = blockIdx.x;
  const int win = bid >> 2, h = bid & 3;   // win-major: 4 head-blocks co-scheduled
  const int iw = win & 15, ih = (win >> 4) & 15, id = win >> 8;
  const int bd = (id == 7), bh = (ih == 15), bw = (iw == 15);

  // ---- stage ALL weights for this head (21760 u16 = 2720 uint4) ----
  {
    const uint4* src = (const uint4*)(wqkv + h * 21760);
    uint4* dst = (uint4*)lds;
    for (int it = tid; it < 2720; it += 448) dst[it] = src[it];
  }
  // ---- gather own A-row straight to registers (no LDS for x) ----
  const int arow = 16 * wv + l15;
  bf16x8 xa[4];
  {
    const bool rok = arow < 98;
    const int rr = rok ? arow : 0;
    int d = rr / 49, rem = rr - d * 49, hh = rem / 7, w2 = rem - hh * 7;
    int pd = (id * 2 + d + 1) & 15;
    int ph = ih * 7 + hh + 3; if (ph >= 112) ph -= 112;
    int pw = iw * 7 + w2 + 3; if (pw >= 112) pw -= 112;
    const float* xp = xg + (((pd * 112 + ph) * 112 + pw) << 7) + lg * 8;
#pragma unroll
    for (int ks = 0; ks < 4; ++ks) {
      float4 a = {0.f, 0.f, 0.f, 0.f}, b4 = {0.f, 0.f, 0.f, 0.f};
      if (rok) {
        a = *(const float4*)(xp + ks * 32);
        b4 = *(const float4*)(xp + ks * 32 + 4);
      }
      u16* xo = (u16*)&xa[ks];
      xo[0] = f2bu(a.x); xo[1] = f2bu(a.y); xo[2] = f2bu(a.z); xo[3] = f2bu(a.w);
      xo[4] = f2bu(b4.x); xo[5] = f2bu(b4.y); xo[6] = f2bu(b4.z); xo[7] = f2bu(b4.w);
    }
  }
  __syncthreads();  // B1: weights staged

  // ---- GEMM1: q,k hi/lo weight-compensated; v plain ----
  const f32x4 zf = {0.f, 0.f, 0.f, 0.f};
  f32x4 aq0 = zf, aq1 = zf, ak0 = zf, ak1 = zf, av0 = zf, av1 = zf;
#pragma unroll
  for (int ks = 0; ks < 4; ++ks) {
    const int k0 = ks * 32 + lg * 8;
    bf16x8 b;
    b = *(const bf16x8*)(&lds[l15 * 136 + k0]);                aq0 = MFMA(xa[ks], b, aq0);
    b = *(const bf16x8*)(&lds[4352 + l15 * 136 + k0]);         aq0 = MFMA(xa[ks], b, aq0);
    b = *(const bf16x8*)(&lds[(16 + l15) * 136 + k0]);         aq1 = MFMA(xa[ks], b, aq1);
    b = *(const bf16x8*)(&lds[4352 + (16 + l15) * 136 + k0]);  aq1 = MFMA(xa[ks], b, aq1);
    b = *(const bf16x8*)(&lds[8704 + l15 * 136 + k0]);         ak0 = MFMA(xa[ks], b, ak0);
    b = *(const bf16x8*)(&lds[13056 + l15 * 136 + k0]);        ak0 = MFMA(xa[ks], b, ak0);
    b = *(const bf16x8*)(&lds[8704 + (16 + l15) * 136 + k0]);  ak1 = MFMA(xa[ks], b, ak1);
    b = *(const bf16x8*)(&lds[13056 + (16 + l15) * 136 + k0]); ak1 = MFMA(xa[ks], b, ak1);
    b = *(const bf16x8*)(&lds[17408 + l15 * 136 + k0]);        av0 = MFMA(xa[ks], b, av0);
    b = *(const bf16x8*)(&lds[17408 + (16 + l15) * 136 + k0]); av1 = MFMA(xa[ks], b, av1);
  }
  __syncthreads();  // B2: weight reads done -> pool reusable

  // ---- phase2: bias, cosine-normalize (scale*log2e folded into q), stores ----
  const float sc2 = __expf(fminf(lscale[h], 4.60517019f)) * LOG2E;
  const float qb0 = qkvb[h * 32 + l15];
  const float qb1 = qkvb[h * 32 + 16 + l15];
  const float vb0 = qkvb[256 + h * 32 + l15];
  const float vb1 = qkvb[256 + h * 32 + 16 + l15];
#pragma unroll
  for (int r = 0; r < 4; ++r) { aq0[r] += qb0; aq1[r] += qb1; av0[r] += vb0; av1[r] += vb1; }
#pragma unroll
  for (int r = 0; r < 4; ++r) {
    const int row = 16 * wv + lg * 4 + r;
    const bool ok = row < 98;
    float s = aq0[r] * aq0[r] + aq1[r] * aq1[r];
    s += __shfl_xor(s, 1); s += __shfl_xor(s, 2); s += __shfl_xor(s, 4); s += __shfl_xor(s, 8);
    float rn = sc2 * rsqrtf(fmaxf(s, 1e-24f));
    float q0 = aq0[r] * rn, q1 = aq1[r] * rn;
    u16 u0 = ok ? f2bu(q0) : (u16)0, u1 = ok ? f2bu(q1) : (u16)0;
    lds[QHI + row * 40 + l15] = u0;
    lds[QHI + row * 40 + 16 + l15] = u1;
    lds[QLO + row * 40 + l15] = ok ? f2bu(q0 - bu2f(u0)) : (u16)0;
    lds[QLO + row * 40 + 16 + l15] = ok ? f2bu(q1 - bu2f(u1)) : (u16)0;
    float sk = ak0[r] * ak0[r] + ak1[r] * ak1[r];
    sk += __shfl_xor(sk, 1); sk += __shfl_xor(sk, 2); sk += __shfl_xor(sk, 4); sk += __shfl_xor(sk, 8);
    float rk = rsqrtf(fmaxf(sk, 1e-24f));
    float k0v = ak0[r] * rk, k1v = ak1[r] * rk;
    u16 ku0 = ok ? f2bu(k0v) : (u16)0, ku1 = ok ? f2bu(k1v) : (u16)0;
    lds[KHI + row * 40 + l15] = ku0;
    lds[KHI + row * 40 + 16 + l15] = ku1;
    lds[KLO + row * 40 + l15] = ok ? f2bu(k0v - bu2f(ku0)) : (u16)0;
    lds[KLO + row * 40 + 16 + l15] = ok ? f2bu(k1v - bu2f(ku1)) : (u16)0;
  }
  {
    const int t0 = 16 * wv + lg * 4;
    ushort4 v0, v1;
    v0.x = (t0 + 0 < 98) ? f2bu(av0[0]) : (u16)0;
    v0.y = (t0 + 1 < 98) ? f2bu(av0[1]) : (u16)0;
    v0.z = (t0 + 2 < 98) ? f2bu(av0[2]) : (u16)0;
    v0.w = (t0 + 3 < 98) ? f2bu(av0[3]) : (u16)0;
    v1.x = (t0 + 0 < 98) ? f2bu(av1[0]) : (u16)0;
    v1.y = (t0 + 1 < 98) ? f2bu(av1[1]) : (u16)0;
    v1.z = (t0 + 2 < 98) ? f2bu(av1[2]) : (u16)0;
    v1.w = (t0 + 3 < 98) ? f2bu(av1[3]) : (u16)0;
    *(ushort4*)(&lds[VIDX(l15, t0)]) = v0;
    *(ushort4*)(&lds[VIDX(16 + l15, t0)]) = v1;
  }
  for (int it = tid; it < 32 * 16; it += 448) {  // zero V^T tok 112..127
    int dd = it >> 4, t = 112 + (it & 15);
    lds[VIDX(dd, t)] = 0;
  }
  __syncthreads();  // B3: Q/K/V^T ready

  // ---- phase3: QK^T (3-term) with rpb+mask as C-operand; softmax in regs ----
  int rcode[4];
#pragma unroll
  for (int r = 0; r < 4; ++r) rcode[r] = maskcode(16 * wv + lg * 4 + r, bd, bh, bw);
  int ccode[7];
#pragma unroll
  for (int c = 0; c < 7; ++c) ccode[c] = maskcode(16 * c + l15, bd, bh, bw);

  const bf16x8 qh = *(const bf16x8*)(&lds[QHI + (16 * wv + l15) * 40 + lg * 8]);
  const bf16x8 qlo = *(const bf16x8*)(&lds[QLO + (16 * wv + l15) * 40 + lg * 8]);
  const float* rbase = rpb + h * 9604;
  f32x4 att[7];
#pragma unroll
  for (int c = 0; c < 7; ++c) {
    const int j = 16 * c + l15;
#pragma unroll
    for (int r = 0; r < 4; ++r) {
      const int i = 16 * wv + lg * 4 + r;
      float v;
      if (j < 98)
        v = (i < 98) ? rbase[i * 98 + j] + (rcode[r] != ccode[c] ? -144.269504f : 0.f) : 0.f;
      else
        v = -1e30f;
      att[c][r] = v;
    }
  }
#pragma unroll
  for (int c = 0; c < 7; ++c) {
    const bf16x8 kh = *(const bf16x8*)(&lds[KHI + (16 * c + l15) * 40 + lg * 8]);
    const bf16x8 kl = *(const bf16x8*)(&lds[KLO + (16 * c + l15) * 40 + lg * 8]);
    att[c] = MFMA(qh, kh, att[c]);
    att[c] = MFMA(qlo, kh, att[c]);
    att[c] = MFMA(qh, kl, att[c]);
  }
  float rsv[4];
#pragma unroll
  for (int r = 0; r < 4; ++r) {
    float s = 0.f;
#pragma unroll
    for (int c = 0; c < 7; ++c) { float p = exp2f(att[c][r]); att[c][r] = p; s += p; }
    s += __shfl_xor(s, 1); s += __shfl_xor(s, 2); s += __shfl_xor(s, 4); s += __shfl_xor(s, 8);
    rsv[r] = 1.0f / s;
  }
  __syncthreads();  // B4: all Q/K reads done -> P may overlay

  // ---- phase4: write P (swizzled), PV, scattered store ----
#pragma unroll
  for (int r = 0; r < 4; ++r) {
    const int i = 16 * wv + lg * 4 + r;
#pragma unroll
    for (int c = 0; c < 8; ++c) {
      const int t = 16 * c + l15;
      lds[PIDX(i, t)] = (c < 7) ? f2bu(att[c][r] * rsv[r]) : (u16)0;
    }
  }
  f32x4 o0 = zf, o1 = zf;
#pragma unroll
  for (int ks = 0; ks < 4; ++ks) {
    const int t = ks * 32 + lg * 8;
    const bf16x8 pa = *(const bf16x8*)(&lds[PIDX(16 * wv + l15, t)]);
    const bf16x8 v0f = *(const bf16x8*)(&lds[VIDX(l15, t)]);
    const bf16x8 v1f = *(const bf16x8*)(&lds[VIDX(16 + l15, t)]);
    o0 = MFMA(pa, v0f, o0);
    o1 = MFMA(pa, v1f, o1);
  }
#pragma unroll
  for (int r = 0; r < 4; ++r) {
    const int row = 16 * wv + lg * 4 + r;
    if (row < 98) {
      int d = row / 49, rem = row - d * 49, hh = rem / 7, w2 = rem - hh * 7;
      int pd = (id * 2 + d + 1) & 15;
      int ph = ih * 7 + hh + 3; if (ph >= 112) ph -= 112;
      int pw = iw * 7 + w2 + 3; if (pw >= 112) pw -= 112;
      const int ob = (((pd * 112 + ph) * 112 + pw) << 7) + h * 32;
      aout[ob + l15] = o0[r];
      aout[ob + 16 + l15] = o1[r];
    }
  }
}

// ---------- proj kernel: one block per window, in-place on d_out ----------
__global__ __launch_bounds__(448) void swin_proj(const u16* __restrict__ wp,
                                                 const float* __restrict__ projb,
                                                 float* io) {
  __shared__ u16 w[17408];
  const int tid = threadIdx.x;
  const int wv = tid >> 6;
  const int l = tid & 63;
  const int l15 = l & 15;
  const int lg = l >> 4;
  const int win = blockIdx.x;
  const int iw = win & 15, ih = (win >> 4) & 15, id = win >> 8;
  {
    const uint4* src = (const uint4*)wp;
    uint4* dst = (uint4*)w;
    for (int it = tid; it < 2176; it += 448) dst[it] = src[it];
  }
  const int arow0 = 16 * wv + l15;
  const int ar = (arow0 < 98) ? arow0 : 97;
  int d = ar / 49, rem = ar - d * 49, hh = rem / 7, w2 = rem - hh * 7;
  int pd = (id * 2 + d + 1) & 15;
  int ph = ih * 7 + hh + 3; if (ph >= 112) ph -= 112;
  int pw = iw * 7 + w2 + 3; if (pw >= 112) pw -= 112;
  const float* abase = io + (((pd * 112 + ph) * 112 + pw) << 7);
  __syncthreads();

  const f32x4 zf = {0.f, 0.f, 0.f, 0.f};
  f32x4 pr[8];
#pragma unroll
  for (int n = 0; n < 8; ++n) pr[n] = zf;
#pragma unroll
  for (int ks = 0; ks < 4; ++ks) {
    const float4 f0 = *(const float4*)(abase + ks * 32 + lg * 8);
    const float4 f1 = *(const float4*)(abase + ks * 32 + lg * 8 + 4);
    bf16x8 oa;
    u16* op = (u16*)&oa;
    op[0] = f2bu(f0.x); op[1] = f2bu(f0.y); op[2] = f2bu(f0.z); op[3] = f2bu(f0.w);
    op[4] = f2bu(f1.x); op[5] = f2bu(f1.y); op[6] = f2bu(f1.z); op[7] = f2bu(f1.w);
#pragma unroll
    for (int n = 0; n < 8; ++n) {
      const bf16x8 wb = *(const bf16x8*)(&w[(16 * n + l15) * 136 + ks * 32 + lg * 8]);
      pr[n] = MFMA(oa, wb, pr[n]);
    }
  }
  int obase[4];
#pragma unroll
  for (int r = 0; r < 4; ++r) {
    const int row = 16 * wv + lg * 4 + r;
    if (row < 98) {
      int d2 = row / 49, rem2 = row - d2 * 49, hh2 = rem2 / 7, w22 = rem2 - hh2 * 7;
      int pd2 = (id * 2 + d2 + 1) & 15;
      int ph2 = ih * 7 + hh2 + 3; if (ph2 >= 112) ph2 -= 112;
      int pw2 = iw * 7 + w22 + 3; if (pw2 >= 112) pw2 -= 112;
      obase[r] = ((pd2 * 112 + ph2) * 112 + pw2) << 7;
    } else obase[r] = -1;
  }
#pragma unroll
  for (int n = 0; n < 8; ++n) {
    const int col = 16 * n + l15;
    const float pb = projb[col];
#pragma unroll
    for (int r = 0; r < 4; ++r) {
      if (obase[r] >= 0) io[obase[r] + col] = pr[n][r] + pb;
    }
  }
}

extern "C" void kernel_launch(void* const* d_in, const int* in_sizes, int n_in,
                              void* d_out, int out_size, void* d_ws, size_t ws_size,
                              hipStream_t stream) {
  const float* xg = (const float*)d_in[0];
  const float* qkvw = (const float*)d_in[1];
  const float* qkvb = (const float*)d_in[2];
  const float* projw = (const float*)d_in[3];
  const float* projb = (const float*)d_in[4];
  const float* lsc = (const float*)d_in[5];
  const float* w1 = (const float*)d_in[6];
  const float* b1 = (const float*)d_in[7];
  const float* w2 = (const float*)d_in[8];

  char* ws = (char*)d_ws;
  float* rpb = (float*)(ws + 0);          // 153,664 B
  float* btab = (float*)(ws + 153664);    // 8,112 B
  u16* wq = (u16*)(ws + 161792);          // 174,080 B
  u16* wp = (u16*)(ws + 335872);          // 34,816 B
  float* io = (float*)d_out;

  cpb_mlp<<<507, 512, 0, stream>>>(w1, b1, w2, btab);
  build_rpb<<<(4 * 98 * 98 + 255) / 256, 256, 0, stream>>>(btab, rpb);
  pack_wqkv<<<640, 136, 0, stream>>>(qkvw, wq);
  pack_wproj<<<128, 136, 0, stream>>>(projw, wp);
  swin_attn<<<8192, 448, 0, stream>>>(xg, qkvb, lsc, rpb, wq, io);
  swin_proj<<<2048, 448, 0, stream>>>(wp, projb, io);
}

// Round 5
// 222.630 us; speedup vs baseline: 2.0974x; 1.3056x over previous
//
#include <hip/hip_runtime.h>

typedef unsigned short u16;
typedef __attribute__((ext_vector_type(8))) short bf16x8;
typedef __attribute__((ext_vector_type(4))) float f32x4;

#define MFMA(a, b, c) __builtin_amdgcn_mfma_f32_16x16x32_bf16((a), (b), (c), 0, 0, 0)
#define LOG2E 1.4426950408889634f

__device__ __forceinline__ u16 f2bu(float f) {  // f32 -> bf16 RNE
  union { float f; unsigned u; } v; v.f = f;
  unsigned r = v.u + 0x7fffu + ((v.u >> 16) & 1u);
  return (u16)(r >> 16);
}
__device__ __forceinline__ float bu2f(u16 u) {
  union { unsigned u; float f; } v; v.u = ((unsigned)u) << 16; return v.f;
}
__device__ __forceinline__ int maskcode(int tok, int bd, int bh, int bw) {
  int d = tok / 49, rem = tok - d * 49, hh = rem / 7, w = rem - hh * 7;
  int rd = bd ? (d == 0 ? 1 : 2) : 0;
  int rh = bh ? (hh < 4 ? 1 : 2) : 0;
  int rw = bw ? (w < 4 ? 1 : 2) : 0;
  return rd * 9 + rh * 3 + rw;
}

// ---------- prep: CPB MLP -> bias_tab[507][4] ----------
__global__ void cpb_mlp(const float* __restrict__ w1, const float* __restrict__ b1,
                        const float* __restrict__ w2, float* __restrict__ btab) {
  const int m = blockIdx.x;          // 0..506
  const int k = threadIdx.x;         // 0..511
  const int i0 = m / 169, rm = m % 169, i1 = rm / 13, i2 = rm % 13;
  float c0 = (float)(i0 - 1) * 8.0f;
  float c1 = (float)(i1 - 6) * (8.0f / 6.0f);
  float c2 = (float)(i2 - 6) * (8.0f / 6.0f);
  float t0 = (c0 > 0.f ? 1.f : (c0 < 0.f ? -1.f : 0.f)) * log2f(fabsf(c0) + 1.f) * (1.f / 3.f);
  float t1 = (c1 > 0.f ? 1.f : (c1 < 0.f ? -1.f : 0.f)) * log2f(fabsf(c1) + 1.f) * (1.f / 3.f);
  float t2 = (c2 > 0.f ? 1.f : (c2 < 0.f ? -1.f : 0.f)) * log2f(fabsf(c2) + 1.f) * (1.f / 3.f);
  float hid = fmaxf(w1[k * 3 + 0] * t0 + w1[k * 3 + 1] * t1 + w1[k * 3 + 2] * t2 + b1[k], 0.f);
  __shared__ float red[4][8];
#pragma unroll
  for (int h = 0; h < 4; ++h) {
    float v = hid * w2[h * 512 + k];
    for (int mm = 1; mm < 64; mm <<= 1) v += __shfl_xor(v, mm);
    if ((k & 63) == 0) red[h][k >> 6] = v;
  }
  __syncthreads();
  if (k < 4) {
    float s = 0.f;
#pragma unroll
    for (int j = 0; j < 8; ++j) s += red[k][j];
    btab[m * 4 + k] = s;
  }
}

// ---------- prep: rpb in MFMA fragment layout with mask folded in ----------
// rpbf[combo][h][wv][c][lane][r] f32 ; combo = bd*4+bh*2+bw
__global__ void build_rpbf(const float* __restrict__ btab, float* __restrict__ rpbf) {
  const int total = 8 * 4 * 7 * 7 * 64 * 4;
  int n = blockIdx.x * 256 + threadIdx.x;
  if (n >= total) return;
  int r = n & 3;
  int lane = (n >> 2) & 63;
  int q = n >> 8;                 // combo*196 + h*49 + wv*7 + c
  int c = q % 7;
  int wv = (q / 7) % 7;
  int h = (q / 49) % 4;
  int combo = q / 196;
  int i = 16 * wv + (lane >> 4) * 4 + r;
  int j = 16 * c + (lane & 15);
  float v;
  if (j >= 98) {
    v = -1e30f;
  } else if (i >= 98) {
    v = 0.f;
  } else {
    int di = i / 49, ri = i % 49, hi_ = ri / 7, wi = ri % 7;
    int dj = j / 49, rj = j % 49, hj = rj / 7, wj = rj % 7;
    int idx = (di - dj + 1) * 169 + (hi_ - hj + 6) * 13 + (wi - wj + 6);
    float b = btab[idx * 4 + h];
    v = (16.f / (1.f + expf(-b))) * LOG2E;
    int bd = (combo >> 2) & 1, bh = (combo >> 1) & 1, bw = combo & 1;
    if (maskcode(i, bd, bh, bw) != maskcode(j, bd, bh, bw)) v -= 144.269504f;
  }
  rpbf[n] = v;
}

// ---------- prep: pack qkv weights per head: [h][5blk][32][136] bf16 (q_hi,q_lo,k_hi,k_lo,v_hi)
__global__ void pack_wqkv(const float* __restrict__ qkvw, u16* __restrict__ dst) {
  int bid = blockIdx.x;                       // 640 = 4h * 5blk * 32r
  int h = bid / 160, rem = bid % 160, blk = rem / 32, r = rem % 32;
  int srow = (blk < 2 ? 0 : (blk < 4 ? 128 : 256)) + h * 32 + r;
  bool lo = (blk == 1) || (blk == 3);
  int c = threadIdx.x;                        // 0..135
  float v = (c < 128) ? qkvw[srow * 128 + c] : 0.f;
  u16 hi = f2bu(v);
  u16 outv = lo ? f2bu(v - bu2f(hi)) : hi;
  dst[h * 21760 + blk * 4352 + r * 136 + c] = outv;
}

// ---------- prep: pack proj weights [128][136] bf16 (row c = output col) ----------
__global__ void pack_wproj(const float* __restrict__ pw, u16* __restrict__ dst) {
  int c = blockIdx.x;                         // 0..127
  int m = threadIdx.x;                        // 0..135
  float v = (m < 128) ? pw[c * 128 + m] : 0.f;
  dst[c * 136 + m] = f2bu(v);
}

// ---------- attention kernel: one block per (window, head), win-major ----------
// LDS pool 18432 u16 (36864 B -> 4 blocks/CU):
//   phase1: staged W q/k hi/lo [4][32][136] = 17408 @0  (V weights streamed from L2)
//   phase2/3: Qhi@0, Qlo@4480, Khi@8960, Klo@13440 (each [112][40])
//   phase4: P [112][128] swz @0 ; VT [32][128] swz @14336
#define QHI 0
#define QLO 4480
#define KHI 8960
#define KLO 13440
#define VTB 14336
#define PIDX(i, t) ((i) * 128 + ((t) ^ (((i) & 7) << 3)))
#define VIDX(d, t) (VTB + (d) * 128 + ((t) ^ (((d) & 7) << 3)))

template <bool BF16OUT>
__global__ __launch_bounds__(448, 7) void swin_attn(
    const float* __restrict__ xg, const float* __restrict__ qkvb,
    const float* __restrict__ lscale, const float* __restrict__ rpbf,
    const u16* __restrict__ wqkv, u16* __restrict__ aoutb, float* __restrict__ aoutf) {
  __shared__ u16 lds[18432];
  const int tid = threadIdx.x;
  const int wv = tid >> 6;
  const int l = tid & 63;
  const int l15 = l & 15;
  const int lg = l >> 4;
  const int bid = blockIdx.x;
  const int win = bid >> 2, h = bid & 3;   // win-major: 4 head-blocks co-scheduled
  const int iw = win & 15, ih = (win >> 4) & 15, id = win >> 8;
  const int combo = ((id == 7) << 2) | ((ih == 15) << 1) | (iw == 15);

  // ---- stage q/k weights (17408 u16 = 2176 uint4) ----
  {
    const uint4* src = (const uint4*)(wqkv + h * 21760);
    uint4* dst = (uint4*)lds;
    for (int it = tid; it < 2176; it += 448) dst[it] = src[it];
  }
  // ---- gather own A-row straight to registers ----
  const int arow = 16 * wv + l15;
  bf16x8 xa[4];
  {
    const bool rok = arow < 98;
    const int rr = rok ? arow : 0;
    int d = rr / 49, rem = rr - d * 49, hh = rem / 7, w2 = rem - hh * 7;
    int pd = (id * 2 + d + 1) & 15;
    int ph = ih * 7 + hh + 3; if (ph >= 112) ph -= 112;
    int pw = iw * 7 + w2 + 3; if (pw >= 112) pw -= 112;
    const float* xp = xg + (((pd * 112 + ph) * 112 + pw) << 7) + lg * 8;
#pragma unroll
    for (int ks = 0; ks < 4; ++ks) {
      float4 a = {0.f, 0.f, 0.f, 0.f}, b4 = {0.f, 0.f, 0.f, 0.f};
      if (rok) {
        a = *(const float4*)(xp + ks * 32);
        b4 = *(const float4*)(xp + ks * 32 + 4);
      }
      u16* xo = (u16*)&xa[ks];
      xo[0] = f2bu(a.x); xo[1] = f2bu(a.y); xo[2] = f2bu(a.z); xo[3] = f2bu(a.w);
      xo[4] = f2bu(b4.x); xo[5] = f2bu(b4.y); xo[6] = f2bu(b4.z); xo[7] = f2bu(b4.w);
    }
  }
  __syncthreads();  // B1: weights staged

  // ---- GEMM1: q,k hi/lo from LDS; v weights streamed from global (L2-hot) ----
  const f32x4 zf = {0.f, 0.f, 0.f, 0.f};
  f32x4 aq0 = zf, aq1 = zf, ak0 = zf, ak1 = zf, av0 = zf, av1 = zf;
  const u16* wvb = wqkv + h * 21760 + 17408 + lg * 8;
  bf16x8 bv0 = *(const bf16x8*)(wvb + l15 * 136);
  bf16x8 bv1 = *(const bf16x8*)(wvb + (16 + l15) * 136);
#pragma unroll
  for (int ks = 0; ks < 4; ++ks) {
    const int k0 = ks * 32 + lg * 8;
    bf16x8 nv0, nv1;
    if (ks < 3) {
      nv0 = *(const bf16x8*)(wvb + l15 * 136 + (ks + 1) * 32);
      nv1 = *(const bf16x8*)(wvb + (16 + l15) * 136 + (ks + 1) * 32);
    }
    bf16x8 b;
    b = *(const bf16x8*)(&lds[l15 * 136 + k0]);                aq0 = MFMA(xa[ks], b, aq0);
    b = *(const bf16x8*)(&lds[4352 + l15 * 136 + k0]);         aq0 = MFMA(xa[ks], b, aq0);
    b = *(const bf16x8*)(&lds[(16 + l15) * 136 + k0]);         aq1 = MFMA(xa[ks], b, aq1);
    b = *(const bf16x8*)(&lds[4352 + (16 + l15) * 136 + k0]);  aq1 = MFMA(xa[ks], b, aq1);
    b = *(const bf16x8*)(&lds[8704 + l15 * 136 + k0]);         ak0 = MFMA(xa[ks], b, ak0);
    b = *(const bf16x8*)(&lds[13056 + l15 * 136 + k0]);        ak0 = MFMA(xa[ks], b, ak0);
    b = *(const bf16x8*)(&lds[8704 + (16 + l15) * 136 + k0]);  ak1 = MFMA(xa[ks], b, ak1);
    b = *(const bf16x8*)(&lds[13056 + (16 + l15) * 136 + k0]); ak1 = MFMA(xa[ks], b, ak1);
    av0 = MFMA(xa[ks], bv0, av0);
    av1 = MFMA(xa[ks], bv1, av1);
    if (ks < 3) { bv0 = nv0; bv1 = nv1; }
  }
  __syncthreads();  // B2: weight reads done -> pool reusable

  // ---- phase2: bias, cosine-normalize (scale*log2e folded into q), Q/K stores ----
  const float sc2 = __expf(fminf(lscale[h], 4.60517019f)) * LOG2E;
  const float qb0 = qkvb[h * 32 + l15];
  const float qb1 = qkvb[h * 32 + 16 + l15];
  const float vb0 = qkvb[256 + h * 32 + l15];
  const float vb1 = qkvb[256 + h * 32 + 16 + l15];
#pragma unroll
  for (int r = 0; r < 4; ++r) { aq0[r] += qb0; aq1[r] += qb1; av0[r] += vb0; av1[r] += vb1; }
#pragma unroll
  for (int r = 0; r < 4; ++r) {
    const int row = 16 * wv + lg * 4 + r;
    const bool ok = row < 98;
    float s = aq0[r] * aq0[r] + aq1[r] * aq1[r];
    s += __shfl_xor(s, 1); s += __shfl_xor(s, 2); s += __shfl_xor(s, 4); s += __shfl_xor(s, 8);
    float rn = sc2 * rsqrtf(fmaxf(s, 1e-24f));
    float q0 = aq0[r] * rn, q1 = aq1[r] * rn;
    u16 u0 = ok ? f2bu(q0) : (u16)0, u1 = ok ? f2bu(q1) : (u16)0;
    lds[QHI + row * 40 + l15] = u0;
    lds[QHI + row * 40 + 16 + l15] = u1;
    lds[QLO + row * 40 + l15] = ok ? f2bu(q0 - bu2f(u0)) : (u16)0;
    lds[QLO + row * 40 + 16 + l15] = ok ? f2bu(q1 - bu2f(u1)) : (u16)0;
    float sk = ak0[r] * ak0[r] + ak1[r] * ak1[r];
    sk += __shfl_xor(sk, 1); sk += __shfl_xor(sk, 2); sk += __shfl_xor(sk, 4); sk += __shfl_xor(sk, 8);
    float rk = rsqrtf(fmaxf(sk, 1e-24f));
    float k0v = ak0[r] * rk, k1v = ak1[r] * rk;
    u16 ku0 = ok ? f2bu(k0v) : (u16)0, ku1 = ok ? f2bu(k1v) : (u16)0;
    lds[KHI + row * 40 + l15] = ku0;
    lds[KHI + row * 40 + 16 + l15] = ku1;
    lds[KLO + row * 40 + l15] = ok ? f2bu(k0v - bu2f(ku0)) : (u16)0;
    lds[KLO + row * 40 + 16 + l15] = ok ? f2bu(k1v - bu2f(ku1)) : (u16)0;
  }
  __syncthreads();  // B3: Q/K ready

  // ---- phase3: QK^T (3-term) with fragment-layout rpb(+mask) as C-init ----
  const bf16x8 qh = *(const bf16x8*)(&lds[QHI + (16 * wv + l15) * 40 + lg * 8]);
  const bf16x8 qlo = *(const bf16x8*)(&lds[QLO + (16 * wv + l15) * 40 + lg * 8]);
  const f32x4* rbf = (const f32x4*)rpbf + (((combo * 4 + h) * 7 + wv) * 7) * 64 + l;
  f32x4 att[7];
#pragma unroll
  for (int c = 0; c < 7; ++c) att[c] = rbf[c * 64];
#pragma unroll
  for (int c = 0; c < 7; ++c) {
    const bf16x8 kh = *(const bf16x8*)(&lds[KHI + (16 * c + l15) * 40 + lg * 8]);
    const bf16x8 kl = *(const bf16x8*)(&lds[KLO + (16 * c + l15) * 40 + lg * 8]);
    att[c] = MFMA(qh, kh, att[c]);
    att[c] = MFMA(qlo, kh, att[c]);
    att[c] = MFMA(qh, kl, att[c]);
  }
  float rsv[4];
#pragma unroll
  for (int r = 0; r < 4; ++r) {
    float s = 0.f;
#pragma unroll
    for (int c = 0; c < 7; ++c) { float p = exp2f(att[c][r]); att[c][r] = p; s += p; }
    s += __shfl_xor(s, 1); s += __shfl_xor(s, 2); s += __shfl_xor(s, 4); s += __shfl_xor(s, 8);
    rsv[r] = 1.0f / s;
  }
  __syncthreads();  // B4: Q/K reads done -> P/VT may overlay

  // ---- phase4: write P + V^T (swizzled), PV, scattered store ----
#pragma unroll
  for (int r = 0; r < 4; ++r) {
    const int i = 16 * wv + lg * 4 + r;
#pragma unroll
    for (int c = 0; c < 8; ++c) {
      const int t = 16 * c + l15;
      lds[PIDX(i, t)] = (c < 7) ? f2bu(att[c][r] * rsv[r]) : (u16)0;
    }
  }
  {
    const int t0 = 16 * wv + lg * 4;
    ushort4 v0, v1;
    v0.x = (t0 + 0 < 98) ? f2bu(av0[0]) : (u16)0;
    v0.y = (t0 + 1 < 98) ? f2bu(av0[1]) : (u16)0;
    v0.z = (t0 + 2 < 98) ? f2bu(av0[2]) : (u16)0;
    v0.w = (t0 + 3 < 98) ? f2bu(av0[3]) : (u16)0;
    v1.x = (t0 + 0 < 98) ? f2bu(av1[0]) : (u16)0;
    v1.y = (t0 + 1 < 98) ? f2bu(av1[1]) : (u16)0;
    v1.z = (t0 + 2 < 98) ? f2bu(av1[2]) : (u16)0;
    v1.w = (t0 + 3 < 98) ? f2bu(av1[3]) : (u16)0;
    *(ushort4*)(&lds[VIDX(l15, t0)]) = v0;
    *(ushort4*)(&lds[VIDX(16 + l15, t0)]) = v1;
  }
  for (int it = tid; it < 32 * 16; it += 448) {  // zero V^T tok 112..127
    int dd = it >> 4, t = 112 + (it & 15);
    lds[VIDX(dd, t)] = 0;
  }
  __syncthreads();  // B5: P/V^T ready

  f32x4 o0 = zf, o1 = zf;
#pragma unroll
  for (int ks = 0; ks < 4; ++ks) {
    const int t = ks * 32 + lg * 8;
    const bf16x8 pa = *(const bf16x8*)(&lds[PIDX(16 * wv + l15, t)]);
    const bf16x8 v0f = *(const bf16x8*)(&lds[VIDX(l15, t)]);
    const bf16x8 v1f = *(const bf16x8*)(&lds[VIDX(16 + l15, t)]);
    o0 = MFMA(pa, v0f, o0);
    o1 = MFMA(pa, v1f, o1);
  }
#pragma unroll
  for (int r = 0; r < 4; ++r) {
    const int row = 16 * wv + lg * 4 + r;
    if (row < 98) {
      int d = row / 49, rem = row - d * 49, hh = rem / 7, w2 = rem - hh * 7;
      int pd = (id * 2 + d + 1) & 15;
      int ph = ih * 7 + hh + 3; if (ph >= 112) ph -= 112;
      int pw = iw * 7 + w2 + 3; if (pw >= 112) pw -= 112;
      const int ob = (((pd * 112 + ph) * 112 + pw) << 7) + h * 32;
      if (BF16OUT) {
        aoutb[ob + l15] = f2bu(o0[r]);
        aoutb[ob + 16 + l15] = f2bu(o1[r]);
      } else {
        aoutf[ob + l15] = o0[r];
        aoutf[ob + 16 + l15] = o1[r];
      }
    }
  }
}

// ---------- proj kernel: one block per window ----------
template <bool BF16OUT>
__global__ __launch_bounds__(448) void swin_proj(const u16* __restrict__ wp,
                                                 const float* __restrict__ projb,
                                                 const u16* __restrict__ aoutb,
                                                 float* io) {
  __shared__ u16 w[17408];
  const int tid = threadIdx.x;
  const int wv = tid >> 6;
  const int l = tid & 63;
  const int l15 = l & 15;
  const int lg = l >> 4;
  const int win = blockIdx.x;
  const int iw = win & 15, ih = (win >> 4) & 15, id = win >> 8;
  {
    const uint4* src = (const uint4*)wp;
    uint4* dst = (uint4*)w;
    for (int it = tid; it < 2176; it += 448) dst[it] = src[it];
  }
  const int arow0 = 16 * wv + l15;
  const int ar = (arow0 < 98) ? arow0 : 97;
  int d = ar / 49, rem = ar - d * 49, hh = rem / 7, w2 = rem - hh * 7;
  int pd = (id * 2 + d + 1) & 15;
  int ph = ih * 7 + hh + 3; if (ph >= 112) ph -= 112;
  int pw = iw * 7 + w2 + 3; if (pw >= 112) pw -= 112;
  const int abase = ((pd * 112 + ph) * 112 + pw) << 7;
  __syncthreads();

  const f32x4 zf = {0.f, 0.f, 0.f, 0.f};
  f32x4 pr[8];
#pragma unroll
  for (int n = 0; n < 8; ++n) pr[n] = zf;
#pragma unroll
  for (int ks = 0; ks < 4; ++ks) {
    bf16x8 oa;
    if (BF16OUT) {
      oa = *(const bf16x8*)(aoutb + abase + ks * 32 + lg * 8);
    } else {
      const float4 f0 = *(const float4*)(io + abase + ks * 32 + lg * 8);
      const float4 f1 = *(const float4*)(io + abase + ks * 32 + lg * 8 + 4);
      u16* op = (u16*)&oa;
      op[0] = f2bu(f0.x); op[1] = f2bu(f0.y); op[2] = f2bu(f0.z); op[3] = f2bu(f0.w);
      op[4] = f2bu(f1.x); op[5] = f2bu(f1.y); op[6] = f2bu(f1.z); op[7] = f2bu(f1.w);
    }
#pragma unroll
    for (int n = 0; n < 8; ++n) {
      const bf16x8 wb = *(const bf16x8*)(&w[(16 * n + l15) * 136 + ks * 32 + lg * 8]);
      pr[n] = MFMA(oa, wb, pr[n]);
    }
  }
  int obase[4];
#pragma unroll
  for (int r = 0; r < 4; ++r) {
    const int row = 16 * wv + lg * 4 + r;
    if (row < 98) {
      int d2 = row / 49, rem2 = row - d2 * 49, hh2 = rem2 / 7, w22 = rem2 - hh2 * 7;
      int pd2 = (id * 2 + d2 + 1) & 15;
      int ph2 = ih * 7 + hh2 + 3; if (ph2 >= 112) ph2 -= 112;
      int pw2 = iw * 7 + w22 + 3; if (pw2 >= 112) pw2 -= 112;
      obase[r] = ((pd2 * 112 + ph2) * 112 + pw2) << 7;
    } else obase[r] = -1;
  }
#pragma unroll
  for (int n = 0; n < 8; ++n) {
    const int col = 16 * n + l15;
    const float pb = projb[col];
#pragma unroll
    for (int r = 0; r < 4; ++r) {
      if (obase[r] >= 0) io[obase[r] + col] = pr[n][r] + pb;
    }
  }
}

extern "C" void kernel_launch(void* const* d_in, const int* in_sizes, int n_in,
                              void* d_out, int out_size, void* d_ws, size_t ws_size,
                              hipStream_t stream) {
  const float* xg = (const float*)d_in[0];
  const float* qkvw = (const float*)d_in[1];
  const float* qkvb = (const float*)d_in[2];
  const float* projw = (const float*)d_in[3];
  const float* projb = (const float*)d_in[4];
  const float* lsc = (const float*)d_in[5];
  const float* w1 = (const float*)d_in[6];
  const float* b1 = (const float*)d_in[7];
  const float* w2 = (const float*)d_in[8];

  char* ws = (char*)d_ws;
  float* btab = (float*)(ws);             // 8,112 B
  u16* wq = (u16*)(ws + 8192);            // 174,080 B -> ends 182,272
  u16* wp = (u16*)(ws + 182272);          // 34,816 B  -> ends 217,088
  float* rpbf = (float*)(ws + 217088);    // 1,605,632 B -> ends 1,822,720
  u16* aoutb = (u16*)(ws + 1822720);      // 51,380,224 B -> ends 53,202,944
  float* io = (float*)d_out;

  const bool bf16path = ws_size >= (size_t)53202944;

  cpb_mlp<<<507, 512, 0, stream>>>(w1, b1, w2, btab);
  build_rpbf<<<(8 * 4 * 7 * 7 * 64 * 4 + 255) / 256, 256, 0, stream>>>(btab, rpbf);
  pack_wqkv<<<640, 136, 0, stream>>>(qkvw, wq);
  pack_wproj<<<128, 136, 0, stream>>>(projw, wp);
  if (bf16path) {
    swin_attn<true><<<8192, 448, 0, stream>>>(xg, qkvb, lsc, rpbf, wq, aoutb, io);
    swin_proj<true><<<2048, 448, 0, stream>>>(wp, projb, aoutb, io);
  } else {
    swin_attn<false><<<8192, 448, 0, stream>>>(xg, qkvb, lsc, rpbf, wq, nullptr, io);
    swin_proj<false><<<2048, 448, 0, stream>>>(wp, projb, nullptr, io);
  }
}

// Round 6
// 218.512 us; speedup vs baseline: 2.1370x; 1.0188x over previous
//
#include <hip/hip_runtime.h>
#include <hip/hip_bf16.h>

typedef unsigned short u16;
typedef __attribute__((ext_vector_type(8))) short bf16x8;
typedef __attribute__((ext_vector_type(4))) float f32x4;

#define MFMA(a, b, c) __builtin_amdgcn_mfma_f32_16x16x32_bf16((a), (b), (c), 0, 0, 0)
#define LOG2E 1.4426950408889634f

__device__ __forceinline__ u16 f2b(float f) {  // f32 -> bf16 RNE via HW cvt
  __hip_bfloat16 h = __float2bfloat16(f);
  return __builtin_bit_cast(u16, h);
}
__device__ __forceinline__ float bu2f(u16 u) {
  union { unsigned u; float f; } v; v.u = ((unsigned)u) << 16; return v.f;
}
__device__ __forceinline__ u16 f2bu_sw(float f) {  // software RNE (prep kernels)
  union { float f; unsigned u; } v; v.f = f;
  unsigned r = v.u + 0x7fffu + ((v.u >> 16) & 1u);
  return (u16)(r >> 16);
}
__device__ __forceinline__ int maskcode(int tok, int bd, int bh, int bw) {
  int d = tok / 49, rem = tok - d * 49, hh = rem / 7, w = rem - hh * 7;
  int rd = bd ? (d == 0 ? 1 : 2) : 0;
  int rh = bh ? (hh < 4 ? 1 : 2) : 0;
  int rw = bw ? (w < 4 ? 1 : 2) : 0;
  return rd * 9 + rh * 3 + rw;
}
// token -> global base index (f32 elements) of shifted position for window (id,ih,iw)
__device__ __forceinline__ int tokbase(int tok, int id, int ih, int iw) {
  int d = tok / 49, rem = tok - d * 49, hh = rem / 7, w2 = rem - hh * 7;
  int pd = (id * 2 + d + 1) & 15;
  int ph = ih * 7 + hh + 3; if (ph >= 112) ph -= 112;
  int pw = iw * 7 + w2 + 3; if (pw >= 112) pw -= 112;
  return ((pd * 112 + ph) * 112 + pw) << 7;
}

// ---------- prep: CPB MLP -> bias_tab[507][4] ----------
__global__ void cpb_mlp(const float* __restrict__ w1, const float* __restrict__ b1,
                        const float* __restrict__ w2, float* __restrict__ btab) {
  const int m = blockIdx.x;          // 0..506
  const int k = threadIdx.x;         // 0..511
  const int i0 = m / 169, rm = m % 169, i1 = rm / 13, i2 = rm % 13;
  float c0 = (float)(i0 - 1) * 8.0f;
  float c1 = (float)(i1 - 6) * (8.0f / 6.0f);
  float c2 = (float)(i2 - 6) * (8.0f / 6.0f);
  float t0 = (c0 > 0.f ? 1.f : (c0 < 0.f ? -1.f : 0.f)) * log2f(fabsf(c0) + 1.f) * (1.f / 3.f);
  float t1 = (c1 > 0.f ? 1.f : (c1 < 0.f ? -1.f : 0.f)) * log2f(fabsf(c1) + 1.f) * (1.f / 3.f);
  float t2 = (c2 > 0.f ? 1.f : (c2 < 0.f ? -1.f : 0.f)) * log2f(fabsf(c2) + 1.f) * (1.f / 3.f);
  float hid = fmaxf(w1[k * 3 + 0] * t0 + w1[k * 3 + 1] * t1 + w1[k * 3 + 2] * t2 + b1[k], 0.f);
  __shared__ float red[4][8];
#pragma unroll
  for (int h = 0; h < 4; ++h) {
    float v = hid * w2[h * 512 + k];
    for (int mm = 1; mm < 64; mm <<= 1) v += __shfl_xor(v, mm);
    if ((k & 63) == 0) red[h][k >> 6] = v;
  }
  __syncthreads();
  if (k < 4) {
    float s = 0.f;
#pragma unroll
    for (int j = 0; j < 8; ++j) s += red[k][j];
    btab[m * 4 + k] = s;
  }
}

// ---------- prep: rpb in MFMA fragment layout with mask folded in ----------
// rpbf[combo][h][wv][c][lane][r] f32 ; combo = bd*4+bh*2+bw
__global__ void build_rpbf(const float* __restrict__ btab, float* __restrict__ rpbf) {
  const int total = 8 * 4 * 7 * 7 * 64 * 4;
  int n = blockIdx.x * 256 + threadIdx.x;
  if (n >= total) return;
  int r = n & 3;
  int lane = (n >> 2) & 63;
  int q = n >> 8;                 // combo*196 + h*49 + wv*7 + c
  int c = q % 7;
  int wv = (q / 7) % 7;
  int h = (q / 49) % 4;
  int combo = q / 196;
  int i = 16 * wv + (lane >> 4) * 4 + r;
  int j = 16 * c + (lane & 15);
  float v;
  if (j >= 98) {
    v = -1e30f;
  } else if (i >= 98) {
    v = 0.f;
  } else {
    int di = i / 49, ri = i % 49, hi_ = ri / 7, wi = ri % 7;
    int dj = j / 49, rj = j % 49, hj = rj / 7, wj = rj % 7;
    int idx = (di - dj + 1) * 169 + (hi_ - hj + 6) * 13 + (wi - wj + 6);
    float b = btab[idx * 4 + h];
    v = (16.f / (1.f + expf(-b))) * LOG2E;
    int bd = (combo >> 2) & 1, bh = (combo >> 1) & 1, bw = combo & 1;
    if (maskcode(i, bd, bh, bw) != maskcode(j, bd, bh, bw)) v -= 144.269504f;
  }
  rpbf[n] = v;
}

// ---------- prep: pack qkv weights per head: [h][5blk][32][136] bf16 (q_hi,q_lo,k_hi,k_lo,v_hi)
__global__ void pack_wqkv(const float* __restrict__ qkvw, u16* __restrict__ dst) {
  int bid = blockIdx.x;                       // 640 = 4h * 5blk * 32r
  int h = bid / 160, rem = bid % 160, blk = rem / 32, r = rem % 32;
  int srow = (blk < 2 ? 0 : (blk < 4 ? 128 : 256)) + h * 32 + r;
  bool lo = (blk == 1) || (blk == 3);
  int c = threadIdx.x;                        // 0..135
  float v = (c < 128) ? qkvw[srow * 128 + c] : 0.f;
  u16 hi = f2bu_sw(v);
  u16 outv = lo ? f2bu_sw(v - bu2f(hi)) : hi;
  dst[h * 21760 + blk * 4352 + r * 136 + c] = outv;
}

// ---------- prep: pack proj weights [128][136] bf16 (row c = output col) ----------
__global__ void pack_wproj(const float* __restrict__ pw, u16* __restrict__ dst) {
  int c = blockIdx.x;                         // 0..127
  int m = threadIdx.x;                        // 0..135
  float v = (m < 128) ? pw[c * 128 + m] : 0.f;
  dst[c * 136 + m] = f2bu_sw(v);
}

// ---------- attention kernel: one block per (window, head), win-major ----------
// LDS pool 18432 u16 (36864 B) + tb[98] int  -> 4 blocks/CU:
//   phase1: staged W q/k hi/lo [4][32][136] = 17408 @0  (V weights streamed from L2)
//   phase2/3: Qhi@0, Qlo@4480, Khi@8960, Klo@13440 (each [112][40])
//   phase4: P [112][128] swz @0 ; VT [32][128] swz @14336
#define QHI 0
#define QLO 4480
#define KHI 8960
#define KLO 13440
#define VTB 14336
#define PIDX(i, t) ((i) * 128 + ((t) ^ (((i) & 7) << 3)))
#define VIDX(d, t) (VTB + (d) * 128 + ((t) ^ (((d) & 7) << 3)))

template <bool BF16OUT>
__global__ __launch_bounds__(448, 7) void swin_attn(
    const float* __restrict__ xg, const float* __restrict__ qkvb,
    const float* __restrict__ lscale, const float* __restrict__ rpbf,
    const u16* __restrict__ wqkv, u16* __restrict__ aoutb, float* __restrict__ aoutf) {
  __shared__ u16 lds[18432];
  __shared__ int tb[98];
  const int tid = threadIdx.x;
  const int wv = tid >> 6;
  const int l = tid & 63;
  const int l15 = l & 15;
  const int lg = l >> 4;
  const int bid = blockIdx.x;
  const int win = bid >> 2, h = bid & 3;   // win-major: 4 head-blocks co-scheduled
  const int iw = win & 15, ih = (win >> 4) & 15, id = win >> 8;
  const int combo = ((id == 7) << 2) | ((ih == 15) << 1) | (iw == 15);

  // ---- token->base table (for epilogue scatter) ----
  if (tid < 98) tb[tid] = tokbase(tid, id, ih, iw);
  // ---- stage q/k weights (17408 u16 = 2176 uint4) ----
  {
    const uint4* src = (const uint4*)(wqkv + h * 21760);
    uint4* dst = (uint4*)lds;
    for (int it = tid; it < 2176; it += 448) dst[it] = src[it];
  }
  // ---- gather own A-row straight to registers ----
  const int arow = 16 * wv + l15;
  bf16x8 xa[4];
  {
    const bool rok = arow < 98;
    const int base = tokbase(rok ? arow : 0, id, ih, iw);
    const float* xp = xg + base + lg * 8;
#pragma unroll
    for (int ks = 0; ks < 4; ++ks) {
      float4 a = {0.f, 0.f, 0.f, 0.f}, b4 = {0.f, 0.f, 0.f, 0.f};
      if (rok) {
        a = *(const float4*)(xp + ks * 32);
        b4 = *(const float4*)(xp + ks * 32 + 4);
      }
      u16* xo = (u16*)&xa[ks];
      xo[0] = f2b(a.x); xo[1] = f2b(a.y); xo[2] = f2b(a.z); xo[3] = f2b(a.w);
      xo[4] = f2b(b4.x); xo[5] = f2b(b4.y); xo[6] = f2b(b4.z); xo[7] = f2b(b4.w);
    }
  }
  __syncthreads();  // B1: weights + tb staged

  // ---- GEMM1: q,k hi/lo from LDS; v weights streamed from global (L2-hot) ----
  const f32x4 zf = {0.f, 0.f, 0.f, 0.f};
  f32x4 aq0 = zf, aq1 = zf, ak0 = zf, ak1 = zf, av0 = zf, av1 = zf;
  const u16* wvb = wqkv + h * 21760 + 17408 + lg * 8;
  bf16x8 bv0 = *(const bf16x8*)(wvb + l15 * 136);
  bf16x8 bv1 = *(const bf16x8*)(wvb + (16 + l15) * 136);
#pragma unroll
  for (int ks = 0; ks < 4; ++ks) {
    const int k0 = ks * 32 + lg * 8;
    bf16x8 nv0, nv1;
    if (ks < 3) {
      nv0 = *(const bf16x8*)(wvb + l15 * 136 + (ks + 1) * 32);
      nv1 = *(const bf16x8*)(wvb + (16 + l15) * 136 + (ks + 1) * 32);
    }
    bf16x8 b;
    b = *(const bf16x8*)(&lds[l15 * 136 + k0]);                aq0 = MFMA(xa[ks], b, aq0);
    b = *(const bf16x8*)(&lds[4352 + l15 * 136 + k0]);         aq0 = MFMA(xa[ks], b, aq0);
    b = *(const bf16x8*)(&lds[(16 + l15) * 136 + k0]);         aq1 = MFMA(xa[ks], b, aq1);
    b = *(const bf16x8*)(&lds[4352 + (16 + l15) * 136 + k0]);  aq1 = MFMA(xa[ks], b, aq1);
    b = *(const bf16x8*)(&lds[8704 + l15 * 136 + k0]);         ak0 = MFMA(xa[ks], b, ak0);
    b = *(const bf16x8*)(&lds[13056 + l15 * 136 + k0]);        ak0 = MFMA(xa[ks], b, ak0);
    b = *(const bf16x8*)(&lds[8704 + (16 + l15) * 136 + k0]);  ak1 = MFMA(xa[ks], b, ak1);
    b = *(const bf16x8*)(&lds[13056 + (16 + l15) * 136 + k0]); ak1 = MFMA(xa[ks], b, ak1);
    av0 = MFMA(xa[ks], bv0, av0);
    av1 = MFMA(xa[ks], bv1, av1);
    if (ks < 3) { bv0 = nv0; bv1 = nv1; }
  }
  __syncthreads();  // B2: weight reads done -> pool reusable

  // ---- phase2: bias, cosine-normalize (scale*log2e folded into q), Q/K stores ----
  const float sc2 = __expf(fminf(lscale[h], 4.60517019f)) * LOG2E;
  const float qb0 = qkvb[h * 32 + l15];
  const float qb1 = qkvb[h * 32 + 16 + l15];
  const float vb0 = qkvb[256 + h * 32 + l15];
  const float vb1 = qkvb[256 + h * 32 + 16 + l15];
#pragma unroll
  for (int r = 0; r < 4; ++r) { aq0[r] += qb0; aq1[r] += qb1; av0[r] += vb0; av1[r] += vb1; }
#pragma unroll
  for (int r = 0; r < 4; ++r) {
    const int row = 16 * wv + lg * 4 + r;
    const bool ok = row < 98;
    float s = aq0[r] * aq0[r] + aq1[r] * aq1[r];
    s += __shfl_xor(s, 1); s += __shfl_xor(s, 2); s += __shfl_xor(s, 4); s += __shfl_xor(s, 8);
    float rn = sc2 * rsqrtf(fmaxf(s, 1e-24f));
    float q0 = ok ? aq0[r] * rn : 0.f, q1 = ok ? aq1[r] * rn : 0.f;
    u16 u0 = f2b(q0), u1 = f2b(q1);
    lds[QHI + row * 40 + l15] = u0;
    lds[QHI + row * 40 + 16 + l15] = u1;
    lds[QLO + row * 40 + l15] = f2b(q0 - bu2f(u0));
    lds[QLO + row * 40 + 16 + l15] = f2b(q1 - bu2f(u1));
    float sk = ak0[r] * ak0[r] + ak1[r] * ak1[r];
    sk += __shfl_xor(sk, 1); sk += __shfl_xor(sk, 2); sk += __shfl_xor(sk, 4); sk += __shfl_xor(sk, 8);
    float rk = rsqrtf(fmaxf(sk, 1e-24f));
    float k0v = ok ? ak0[r] * rk : 0.f, k1v = ok ? ak1[r] * rk : 0.f;
    u16 ku0 = f2b(k0v), ku1 = f2b(k1v);
    lds[KHI + row * 40 + l15] = ku0;
    lds[KHI + row * 40 + 16 + l15] = ku1;
    lds[KLO + row * 40 + l15] = f2b(k0v - bu2f(ku0));
    lds[KLO + row * 40 + 16 + l15] = f2b(k1v - bu2f(ku1));
  }
  __syncthreads();  // B3: Q/K ready

  // ---- phase3: QK^T (3-term) with fragment-layout rpb(+mask) as C-init ----
  const bf16x8 qh = *(const bf16x8*)(&lds[QHI + (16 * wv + l15) * 40 + lg * 8]);
  const bf16x8 qlo = *(const bf16x8*)(&lds[QLO + (16 * wv + l15) * 40 + lg * 8]);
  const f32x4* rbf = (const f32x4*)rpbf + (((combo * 4 + h) * 7 + wv) * 7) * 64 + l;
  f32x4 att[7];
#pragma unroll
  for (int c = 0; c < 7; ++c) att[c] = rbf[c * 64];
#pragma unroll
  for (int c = 0; c < 7; ++c) {
    const bf16x8 kh = *(const bf16x8*)(&lds[KHI + (16 * c + l15) * 40 + lg * 8]);
    const bf16x8 kl = *(const bf16x8*)(&lds[KLO + (16 * c + l15) * 40 + lg * 8]);
    att[c] = MFMA(qh, kh, att[c]);
    att[c] = MFMA(qlo, kh, att[c]);
    att[c] = MFMA(qh, kl, att[c]);
  }
  float rsv[4];
#pragma unroll
  for (int r = 0; r < 4; ++r) {
    float s = 0.f;
#pragma unroll
    for (int c = 0; c < 7; ++c) { float p = exp2f(att[c][r]); att[c][r] = p; s += p; }
    s += __shfl_xor(s, 1); s += __shfl_xor(s, 2); s += __shfl_xor(s, 4); s += __shfl_xor(s, 8);
    rsv[r] = 1.0f / s;
  }
  __syncthreads();  // B4: Q/K reads done -> P/VT may overlay

  // ---- phase4: write P + V^T (swizzled), PV, scattered store ----
#pragma unroll
  for (int r = 0; r < 4; ++r) {
    const int i = 16 * wv + lg * 4 + r;
#pragma unroll
    for (int c = 0; c < 8; ++c) {
      const int t = 16 * c + l15;
      lds[PIDX(i, t)] = (c < 7) ? f2b(att[c][r] * rsv[r]) : (u16)0;
    }
  }
  {
    const int t0 = 16 * wv + lg * 4;
    ushort4 v0, v1;
    v0.x = (t0 + 0 < 98) ? f2b(av0[0]) : (u16)0;
    v0.y = (t0 + 1 < 98) ? f2b(av0[1]) : (u16)0;
    v0.z = (t0 + 2 < 98) ? f2b(av0[2]) : (u16)0;
    v0.w = (t0 + 3 < 98) ? f2b(av0[3]) : (u16)0;
    v1.x = (t0 + 0 < 98) ? f2b(av1[0]) : (u16)0;
    v1.y = (t0 + 1 < 98) ? f2b(av1[1]) : (u16)0;
    v1.z = (t0 + 2 < 98) ? f2b(av1[2]) : (u16)0;
    v1.w = (t0 + 3 < 98) ? f2b(av1[3]) : (u16)0;
    *(ushort4*)(&lds[VIDX(l15, t0)]) = v0;
    *(ushort4*)(&lds[VIDX(16 + l15, t0)]) = v1;
  }
  for (int it = tid; it < 32 * 16; it += 448) {  // zero V^T tok 112..127
    int dd = it >> 4, t = 112 + (it & 15);
    lds[VIDX(dd, t)] = 0;
  }
  __syncthreads();  // B5: P/V^T ready

  f32x4 o0 = zf, o1 = zf;
#pragma unroll
  for (int ks = 0; ks < 4; ++ks) {
    const int t = ks * 32 + lg * 8;
    const bf16x8 pa = *(const bf16x8*)(&lds[PIDX(16 * wv + l15, t)]);
    const bf16x8 v0f = *(const bf16x8*)(&lds[VIDX(l15, t)]);
    const bf16x8 v1f = *(const bf16x8*)(&lds[VIDX(16 + l15, t)]);
    o0 = MFMA(pa, v0f, o0);
    o1 = MFMA(pa, v1f, o1);
  }
#pragma unroll
  for (int r = 0; r < 4; ++r) {
    const int row = 16 * wv + lg * 4 + r;
    if (row < 98) {
      const int ob = tb[row] + h * 32;
      if (BF16OUT) {
        aoutb[ob + l15] = f2b(o0[r]);
        aoutb[ob + 16 + l15] = f2b(o1[r]);
      } else {
        aoutf[ob + l15] = o0[r];
        aoutf[ob + 16 + l15] = o1[r];
      }
    }
  }
}

// ---------- proj kernel: one block per window ----------
template <bool BF16OUT>
__global__ __launch_bounds__(448) void swin_proj(const u16* __restrict__ wp,
                                                 const float* __restrict__ projb,
                                                 const u16* __restrict__ aoutb,
                                                 float* io) {
  __shared__ u16 w[17408];
  __shared__ int tb[98];
  const int tid = threadIdx.x;
  const int wv = tid >> 6;
  const int l = tid & 63;
  const int l15 = l & 15;
  const int lg = l >> 4;
  const int win = blockIdx.x;
  const int iw = win & 15, ih = (win >> 4) & 15, id = win >> 8;
  if (tid < 98) tb[tid] = tokbase(tid, id, ih, iw);
  {
    const uint4* src = (const uint4*)wp;
    uint4* dst = (uint4*)w;
    for (int it = tid; it < 2176; it += 448) dst[it] = src[it];
  }
  __syncthreads();
  const int arow0 = 16 * wv + l15;
  const int abase = tb[(arow0 < 98) ? arow0 : 97];

  const f32x4 zf = {0.f, 0.f, 0.f, 0.f};
  f32x4 pr[8];
#pragma unroll
  for (int n = 0; n < 8; ++n) pr[n] = zf;
#pragma unroll
  for (int ks = 0; ks < 4; ++ks) {
    bf16x8 oa;
    if (BF16OUT) {
      oa = *(const bf16x8*)(aoutb + abase + ks * 32 + lg * 8);
    } else {
      const float4 f0 = *(const float4*)(io + abase + ks * 32 + lg * 8);
      const float4 f1 = *(const float4*)(io + abase + ks * 32 + lg * 8 + 4);
      u16* op = (u16*)&oa;
      op[0] = f2b(f0.x); op[1] = f2b(f0.y); op[2] = f2b(f0.z); op[3] = f2b(f0.w);
      op[4] = f2b(f1.x); op[5] = f2b(f1.y); op[6] = f2b(f1.z); op[7] = f2b(f1.w);
    }
#pragma unroll
    for (int n = 0; n < 8; ++n) {
      const bf16x8 wb = *(const bf16x8*)(&w[(16 * n + l15) * 136 + ks * 32 + lg * 8]);
      pr[n] = MFMA(oa, wb, pr[n]);
    }
  }
#pragma unroll
  for (int n = 0; n < 8; ++n) {
    const int col = 16 * n + l15;
    const float pb = projb[col];
#pragma unroll
    for (int r = 0; r < 4; ++r) {
      const int row = 16 * wv + lg * 4 + r;
      if (row < 98) io[tb[row] + col] = pr[n][r] + pb;
    }
  }
}

extern "C" void kernel_launch(void* const* d_in, const int* in_sizes, int n_in,
                              void* d_out, int out_size, void* d_ws, size_t ws_size,
                              hipStream_t stream) {
  const float* xg = (const float*)d_in[0];
  const float* qkvw = (const float*)d_in[1];
  const float* qkvb = (const float*)d_in[2];
  const float* projw = (const float*)d_in[3];
  const float* projb = (const float*)d_in[4];
  const float* lsc = (const float*)d_in[5];
  const float* w1 = (const float*)d_in[6];
  const float* b1 = (const float*)d_in[7];
  const float* w2 = (const float*)d_in[8];

  char* ws = (char*)d_ws;
  float* btab = (float*)(ws);             // 8,112 B
  u16* wq = (u16*)(ws + 8192);            // 174,080 B -> ends 182,272
  u16* wp = (u16*)(ws + 182272);          // 34,816 B  -> ends 217,088
  float* rpbf = (float*)(ws + 217088);    // 1,605,632 B -> ends 1,822,720
  u16* aoutb = (u16*)(ws + 1822720);      // 51,380,224 B -> ends 53,202,944
  float* io = (float*)d_out;

  const bool bf16path = ws_size >= (size_t)53202944;

  cpb_mlp<<<507, 512, 0, stream>>>(w1, b1, w2, btab);
  build_rpbf<<<(8 * 4 * 7 * 7 * 64 * 4 + 255) / 256, 256, 0, stream>>>(btab, rpbf);
  pack_wqkv<<<640, 136, 0, stream>>>(qkvw, wq);
  pack_wproj<<<128, 136, 0, stream>>>(projw, wp);
  if (bf16path) {
    swin_attn<true><<<8192, 448, 0, stream>>>(xg, qkvb, lsc, rpbf, wq, aoutb, io);
    swin_proj<true><<<2048, 448, 0, stream>>>(wp, projb, aoutb, io);
  } else {
    swin_attn<false><<<8192, 448, 0, stream>>>(xg, qkvb, lsc, rpbf, wq, nullptr, io);
    swin_proj<false><<<2048, 448, 0, stream>>>(wp, projb, nullptr, io);
  }
}